// Round 4
// 2185.946 us; speedup vs baseline: 1.6751x; 1.6751x over previous
//
#include <hip/hip_runtime.h>
#include <stdint.h>

#define HH_ 64
#define WW_ 64
#define NB 4
#define CIN 1024
#define CMID 512
#define NANCH (HH_*WW_*9)      // 36864
#define PRE_N 6000
#define POST_N 300
#define CAND_PAD 6144
#define NEGV (-1.0e10f)
#define TOTIN (NB*CIN*4096)    // 16,777,216 floats in base_feat
#define LO_SCL 2048.0f         // 2^11
#define LO_INV 4.8828125e-4f   // 2^-11

typedef unsigned short u16;
typedef __attribute__((ext_vector_type(8))) _Float16 f16x8;
typedef __attribute__((ext_vector_type(4))) float f32x4;

#define AS1 __attribute__((address_space(1)))
#define AS3 __attribute__((address_space(3)))

// ---------------- workspace layout (float units) ----------------
// total = 13,991,936 floats = 55.97 MB (<= 57.3 MB proven)
#define X_OFF   0
#define X_SZ    (NB*CMID*HH_*WW_)        // 8,388,608
#define SC_OFF  (X_OFF + X_SZ)
#define SC_SZ   (NB*NANCH)               // 147,456
#define BX_OFF  (SC_OFF + SC_SZ)
#define BX_SZ   (NB*NANCH*4)             // 589,824
#define CSC_OFF (BX_OFF + BX_SZ)
#define CSC_SZ  (NB*CAND_PAD)
#define CBX_OFF (CSC_OFF + CSC_SZ)
#define CBX_SZ  (NB*CAND_PAD*4)
#define CIX_OFF (CBX_OFF + CBX_SZ)
#define CIX_SZ  (NB*CAND_PAD)
#define WTH_OFF (CIX_OFF + CIX_SZ)
#define WTH_SZ  (9*512*1024/2)           // fp16 hi weights [r][co][ci_perm]
#define WTL_OFF (WTH_OFF + WTH_SZ)
#define WTL_SZ  WTH_SZ

// ---------------- helpers ----------------
__device__ __forceinline__ void gl2lds16(const void* g, void* l) {
    __builtin_amdgcn_global_load_lds((const AS1 unsigned int*)g,
                                     (AS3 unsigned int*)l, 16, 0, 0);
}
union fh_u { _Float16 h; u16 u; };
__device__ __forceinline__ u16 f2h_hi(float x) {
    fh_u c; c.h = (_Float16)x; return c.u;
}
__device__ __forceinline__ u16 f2h_lo(float x, u16 hi) {
    fh_u c; c.u = hi;
    float hf = (float)c.h;
    fh_u d; d.h = (_Float16)((x - hf) * LO_SCL);
    return d.u;
}
// slot->channel map within each 32-chunk (matches MFMA per-lane k grouping):
// slot 8h+j holds channel c = (j<4) ? 4h+j : 16+4h+(j-4).
// cperm(c) is the inverse (channel -> slot). Applied identically to A and B,
// so the contraction is invariant to whether HW uses this or contiguous k.
__device__ __forceinline__ int cperm(int c) {
    int blk = c >> 5, w = c & 31;
    int pos = (w < 16) ? (((w >> 2) << 3) + (w & 3))
                       : ((((w - 16) >> 2) << 3) + 4 + (w & 3));
    return (blk << 5) + pos;
}

// =====================================================================
// Prep: conv weights fp32 [co][ci][3][3] -> fp16 hi / scaled-lo
// [r][co][ci_perm].  w = hi + lo*2^-11, |err| ~ 2^-22 rel.
// =====================================================================
__global__ __launch_bounds__(256) void prep_wtk(
    const float* __restrict__ conv_w, u16* __restrict__ WTH,
    u16* __restrict__ WTL)
{
    int o = blockIdx.x * 256 + threadIdx.x;      // < 4,718,592
    int ci = o & 1023, co = (o >> 10) & 511, r = o >> 19;
    float v = conv_w[((size_t)(co * 1024 + ci)) * 9 + r];
    u16 h  = f2h_hi(v);
    u16 lo = f2h_lo(v, h);
    size_t d = (((size_t)(r * 512 + co)) << 10) + cperm(ci);
    WTH[d] = h; WTL[d] = lo;
}

// =====================================================================
// Kernel 1: 3x3 conv as scaled-split-fp16 MFMA implicit GEMM.
// acc0 = Ah*Bh ; acc1 = Ah*Bl + Al*Bh ; C = acc0 + acc1*2^-11.
// Per-term rel err ~3*2^-22 (below fp32 reorder noise).
// M=512(co) N=16384(b,y,x) K=9216. 128x128 tile, BK=32, 256 thr
// (2x2 waves, 4x4 16x16x32 frags), dbuf LDS 64KB.
// A: global_load_lds from pre-split WTH/WTL (linear [row][32slot]).
// B: reg-staged fp32 -> split in regs -> ds_write, XOR swizzle
//    n_low2 ^= chunk. Per-element halo masking; addresses clamped.
// =====================================================================
__global__ __launch_bounds__(256, 2) void conv3_mfma(
    const u16* __restrict__ WTH, const u16* __restrict__ WTL,
    const float* __restrict__ IN, const float* __restrict__ bias,
    float* __restrict__ Xout)
{
    __shared__ u16 Ah_s[2][4096];
    __shared__ u16 Al_s[2][4096];
    __shared__ u16 Bh_s[2][4096];   // [chunk][n_phys][8] per buffer
    __shared__ u16 Bl_s[2][4096];

    const int tid = threadIdx.x;
    const int bn  = blockIdx.x;              // 0..127
    const int bm  = blockIdx.y;              // 0..3
    const int l   = tid & 63;
    const int wid = tid >> 6, wm = wid >> 1, wn = wid & 1;

    // ---- A staging map (gl_lds, linear): row rowq, 16B chunk c8 ----
    const int rowq = tid >> 2;               // 0..63
    const int c8   = (tid & 3) << 3;

    // ---- B load/convert map: quad g (4 ci), 4 n-rows ----
    const int g    = tid & 7;                // ci quad: channels 4g..4g+3
    const int ng   = tid >> 3;               // 0..31 -> n rows 4ng..4ng+3
    const int h    = g & 3;                  // LDS chunk
    const int half = g >> 2;                 // half within chunk
    const int nr0  = ng << 2;

    const int b_img   = bn >> 5;
    const int base_sp = (bn & 31) << 7;
    const int yy      = ((bn & 31) << 1) + (ng >> 4);   // this thread's y

    f32x4 acc0[4][4], acc1[4][4];
#pragma unroll
    for (int i = 0; i < 4; i++)
#pragma unroll
        for (int j = 0; j < 4; j++) { acc0[i][j] = (f32x4)0.f; acc1[i][j] = (f32x4)0.f; }

    const int NK = 288;                      // 9216/32

    auto issueA = [&](int kt, int sb) {
        const int r   = kt >> 5;
        const int ci0 = (kt & 31) << 5;
        const size_t wbase = (((size_t)(r * 512 + bm * 128)) << 10) + ci0 + c8;
        u16* ah = &Ah_s[sb][tid * 8];
        u16* al = &Al_s[sb][tid * 8];
#pragma unroll
        for (int q = 0; q < 2; q++) {
            const size_t aoff = wbase + (((size_t)(q * 64 + rowq)) << 10);
            gl2lds16(WTH + aoff, ah + q * 2048);
            gl2lds16(WTL + aoff, al + q * 2048);
        }
    };

    float rb[4][4];                          // [jc][jn]
    auto loadB = [&](int kt) {
        const int r   = kt >> 5;
        const int ci0 = (kt & 31) << 5;
        const int kr  = (r * 11) >> 5;       // r/3
        const int sh  = (kr - 1) * 64 + (r - 3 * kr - 1);
#pragma unroll
        for (int jc = 0; jc < 4; jc++) {
            const int ci = ci0 + (g << 2) + jc;
            const int base = ((b_img << 10) + ci) * 4096 + base_sp + nr0 + sh;
#pragma unroll
            for (int jn = 0; jn < 4; jn++) {
                int a = base + jn;
                a = a < 0 ? 0 : (a > TOTIN - 1 ? TOTIN - 1 : a);
                rb[jc][jn] = IN[a];
            }
        }
    };

    auto convB = [&](int sb, int kt) {
        const int r  = kt >> 5;
        const int kr = (r * 11) >> 5;
        const int dx = r - 3 * kr - 1;
        const int dy = kr - 1;
        const bool vy = ((unsigned)(yy + dy) < 64u);
#pragma unroll
        for (int jn = 0; jn < 4; jn++) {
            const int nr = nr0 + jn;
            const bool v = vy && ((unsigned)((nr & 63) + dx) < 64u);
            u16 hs[4], ls[4];
#pragma unroll
            for (int jc = 0; jc < 4; jc++) {
                float x = v ? rb[jc][jn] : 0.f;
                u16 hb = f2h_hi(x);
                hs[jc] = hb;
                ls[jc] = f2h_lo(x, hb);
            }
            const int np = (nr & ~3) | ((nr & 3) ^ h);
            const int ad = (h << 10) + (np << 3) + (half << 2);
            uint2 ph, pl;
            ph.x = (unsigned)hs[0] | ((unsigned)hs[1] << 16);
            ph.y = (unsigned)hs[2] | ((unsigned)hs[3] << 16);
            pl.x = (unsigned)ls[0] | ((unsigned)ls[1] << 16);
            pl.y = (unsigned)ls[2] | ((unsigned)ls[3] << 16);
            *(uint2*)&Bh_s[sb][ad] = ph;
            *(uint2*)&Bl_s[sb][ad] = pl;
        }
    };

    // ---- prologue ----
    loadB(0);
    issueA(0, 0);
    convB(0, 0);        // waits rb(tile0), ds_writes tile0 -> B[0]
    loadB(1);           // tile1 fp32 in flight

    int buf = 0;
    for (int kt = 0; kt < NK; ++kt) {
        __syncthreads();                       // A[buf] landed; B[buf] writes drained
        if (kt + 1 < NK) {
            issueA(kt + 1, buf ^ 1);
            convB(buf ^ 1, kt + 1);            // write next tile from regs
        }
        if (kt + 2 < NK) loadB(kt + 2);        // issue-early (T14)
        {
            const int lo16 = l & 15, hi4 = l >> 4;
            const int arow = (wm * 64 + lo16) * 32 + hi4 * 8;
            f16x8 ah[4], av[4], bh[4], bv[4];
#pragma unroll
            for (int i = 0; i < 4; i++) {
                ah[i] = *(const f16x8*)&Ah_s[buf][arow + i * 512];
                av[i] = *(const f16x8*)&Al_s[buf][arow + i * 512];
                const int nl = wn * 64 + i * 16 + lo16;
                const int np = (nl & ~3) | ((nl & 3) ^ hi4);
                const int ba = (hi4 << 10) + (np << 3);
                bh[i] = *(const f16x8*)&Bh_s[buf][ba];
                bv[i] = *(const f16x8*)&Bl_s[buf][ba];
            }
#pragma unroll
            for (int mi = 0; mi < 4; mi++)
#pragma unroll
                for (int ni = 0; ni < 4; ni++) {
                    acc0[mi][ni] = __builtin_amdgcn_mfma_f32_16x16x32_f16(
                        ah[mi], bh[ni], acc0[mi][ni], 0, 0, 0);
                    acc1[mi][ni] = __builtin_amdgcn_mfma_f32_16x16x32_f16(
                        ah[mi], bv[ni], acc1[mi][ni], 0, 0, 0);
                    acc1[mi][ni] = __builtin_amdgcn_mfma_f32_16x16x32_f16(
                        av[mi], bh[ni], acc1[mi][ni], 0, 0, 0);
                }
        }
        buf ^= 1;
    }

    // epilogue: combine + bias + relu -> X NCHW fp32.
    // C/D map: col(n)=lane&15, row(co)=(lane>>4)*4+reg  [m89/m91-verified]
#pragma unroll
    for (int mi = 0; mi < 4; mi++) {
        const int co0 = bm * 128 + wm * 64 + mi * 16 + ((l >> 4) << 2);
        const f32x4 b4 = *(const f32x4*)&bias[co0];
#pragma unroll
        for (int ni = 0; ni < 4; ni++) {
            const int n = bn * 128 + wn * 64 + ni * 16 + (l & 15);
            const int b = n >> 12, sp = n & 4095;
            f32x4 v0 = acc0[mi][ni], v1 = acc1[mi][ni];
            float* xo = Xout + (((size_t)(b * 512 + co0)) << 12) + sp;
            xo[0]        = fmaxf(fmaf(v1[0], LO_INV, v0[0]) + b4[0], 0.f);
            xo[4096]     = fmaxf(fmaf(v1[1], LO_INV, v0[1]) + b4[1], 0.f);
            xo[2 * 4096] = fmaxf(fmaf(v1[2], LO_INV, v0[2]) + b4[2], 0.f);
            xo[3 * 4096] = fmaxf(fmaf(v1[3], LO_INV, v0[3]) + b4[3], 0.f);
        }
    }
}

// =====================================================================
// Kernel 2: 1x1 heads + softmax + box decode + clip (unchanged).
// =====================================================================
__global__ __launch_bounds__(256) void heads_kernel(
    const float* __restrict__ X, const float* __restrict__ cls_w,
    const float* __restrict__ cls_b, const float* __restrict__ bbox_w,
    const float* __restrict__ bbox_b, const float* __restrict__ im_info,
    float* __restrict__ SC, float* __restrict__ BXo)
{
    __shared__ float Ws[54][64];
    const int tid = threadIdx.x;
    const int blk = blockIdx.x;            // 0..63
    const int b   = blk >> 4;
    const int s   = ((blk & 15) << 8) + tid;

    float acc[54];
#pragma unroll
    for (int j = 0; j < 18; j++) acc[j] = cls_b[j];
#pragma unroll
    for (int j = 0; j < 36; j++) acc[18 + j] = bbox_b[j];

    const float* xp = X + (size_t)b * CMID * 4096 + s;
    for (int c0 = 0; c0 < 512; c0 += 64) {
        __syncthreads();
        for (int e = tid; e < 54 * 64; e += 256) {
            int j = e >> 6, ci = e & 63;
            Ws[j][ci] = (j < 18) ? cls_w[j * 512 + c0 + ci]
                                 : bbox_w[(j - 18) * 512 + c0 + ci];
        }
        __syncthreads();
        for (int ci = 0; ci < 64; ci += 4) {
            float x0 = xp[(size_t)(c0 + ci) * 4096];
            float x1 = xp[(size_t)(c0 + ci + 1) * 4096];
            float x2 = xp[(size_t)(c0 + ci + 2) * 4096];
            float x3 = xp[(size_t)(c0 + ci + 3) * 4096];
#pragma unroll
            for (int j = 0; j < 54; j++) {
                float4 w4 = *(const float4*)&Ws[j][ci];
                acc[j] = fmaf(x3, w4.w, fmaf(x2, w4.z, fmaf(x1, w4.y, fmaf(x0, w4.x, acc[j]))));
            }
        }
    }

    const float imh = im_info[b * 3 + 0];
    const float imw = im_info[b * 3 + 1];
    const int hh = s >> 6, ww = s & 63;
    const float cxa = 7.5f + 16.f * (float)ww;
    const float cya = 7.5f + 16.f * (float)hh;
    const float WA[9] = {184.f, 368.f, 736.f, 128.f, 256.f, 512.f, 88.f, 176.f, 352.f};
    const float HA[9] = {96.f, 192.f, 384.f, 128.f, 256.f, 512.f, 176.f, 352.f, 704.f};
    const size_t base = (size_t)b * NANCH + (size_t)s * 9;
#pragma unroll
    for (int c = 0; c < 9; c++) {
        float bg = acc[c], fg = acc[9 + c];
        float m  = fmaxf(bg, fg);
        float e0 = expf(bg - m), e1 = expf(fg - m);
        float p  = e1 / (e0 + e1);
        float dx = acc[18 + 4 * c], dy = acc[19 + 4 * c];
        float dw = acc[20 + 4 * c], dh = acc[21 + 4 * c];
        float wa = WA[c], ha = HA[c];
        float cx = dx * wa + cxa;
        float cy = dy * ha + cya;
        float pw = expf(dw) * wa;
        float ph = expf(dh) * ha;
        float x1 = cx - 0.5f * pw, y1 = cy - 0.5f * ph;
        float x2 = cx + 0.5f * pw, y2 = cy + 0.5f * ph;
        x1 = fminf(fmaxf(x1, 0.f), imw - 1.f);
        y1 = fminf(fmaxf(y1, 0.f), imh - 1.f);
        x2 = fminf(fmaxf(x2, 0.f), imw - 1.f);
        y2 = fminf(fmaxf(y2, 0.f), imh - 1.f);
        SC[base + c] = p;
        *(float4*)&BXo[(base + c) * 4] = make_float4(x1, y1, x2, y2);
    }
}

// =====================================================================
// Kernel 3: per-batch exact top-6000 selection (unchanged).
// =====================================================================
__global__ __launch_bounds__(1024) void select_kernel(
    const float* __restrict__ SC, const float* __restrict__ BX,
    float* __restrict__ CSC, float* __restrict__ CBX, int* __restrict__ CIX)
{
    const int b = blockIdx.x, tid = threadIdx.x;
    const float* sc = SC + (size_t)b * NANCH;
    const unsigned* bits = (const unsigned*)sc;
    __shared__ int s_cnt;
    __shared__ int s_c1, s_c2;
    __shared__ int s_tie[8192];

    unsigned lo = 0u, hi = 0x3f800001u;
    while (hi - lo > 1u) {
        unsigned mid = lo + ((hi - lo) >> 1);
        if (tid == 0) s_cnt = 0;
        __syncthreads();
        int c = 0;
        for (int i = tid; i < NANCH; i += 1024) c += (bits[i] >= mid) ? 1 : 0;
#pragma unroll
        for (int off = 32; off; off >>= 1) c += __shfl_down(c, off);
        if ((tid & 63) == 0) atomicAdd(&s_cnt, c);
        __syncthreads();
        int total = s_cnt;
        __syncthreads();
        if (total >= PRE_N) lo = mid; else hi = mid;
    }
    const unsigned ustar = lo;

    if (tid == 0) s_cnt = 0;
    __syncthreads();
    {
        int c = 0;
        for (int i = tid; i < NANCH; i += 1024) c += (bits[i] > ustar) ? 1 : 0;
#pragma unroll
        for (int off = 32; off; off >>= 1) c += __shfl_down(c, off);
        if ((tid & 63) == 0) atomicAdd(&s_cnt, c);
    }
    __syncthreads();
    const int n1 = s_cnt;
    __syncthreads();

    if (tid == 0) { s_c1 = 0; s_c2 = 0; }
    __syncthreads();

    const float4* bx4 = (const float4*)BX + (size_t)b * NANCH;
    float4* cbx4 = (float4*)CBX + (size_t)b * CAND_PAD;
    float*  csc  = CSC + (size_t)b * CAND_PAD;
    int*    cix  = CIX + (size_t)b * CAND_PAD;

    for (int i = tid; i < NANCH; i += 1024) {
        unsigned u = bits[i];
        if (u > ustar) {
            int p = atomicAdd(&s_c1, 1);
            csc[p] = sc[i]; cbx4[p] = bx4[i]; cix[p] = i;
        } else if (u == ustar) {
            int p = atomicAdd(&s_c2, 1);
            if (p < 8192) s_tie[p] = i;
        }
    }
    __syncthreads();
    int m = s_c2; if (m > 8192) m = 8192;
    const int need = PRE_N - n1;
    for (int i = tid; i < 8192; i += 1024)
        if (i >= m) s_tie[i] = 0x7fffffff;
    __syncthreads();

    for (int k = 2; k <= 8192; k <<= 1) {
        for (int j = k >> 1; j > 0; j >>= 1) {
            for (int t = tid; t < 8192; t += 1024) {
                int ixj = t ^ j;
                if (ixj > t) {
                    int va = s_tie[t], vb = s_tie[ixj];
                    bool up = ((t & k) == 0);
                    if ((va > vb) == up) { s_tie[t] = vb; s_tie[ixj] = va; }
                }
            }
            __syncthreads();
        }
    }
    for (int t = tid; t < need; t += 1024) {
        int i = s_tie[t];
        int p = n1 + t;
        if (i >= 0 && i < NANCH) {
            csc[p] = sc[i]; cbx4[p] = bx4[i]; cix[p] = i;
        } else {
            csc[p] = -2.0e10f; cix[p] = 0x7fffffff;
            cbx4[p] = make_float4(-4e9f, -4e9f, -4e9f, -4e9f);
        }
    }
    for (int p = PRE_N + tid; p < CAND_PAD; p += 1024) {
        csc[p] = -2.0e10f;
        cix[p] = 0x7fffffff;
        cbx4[p] = make_float4(-4e9f, -4e9f, -4e9f, -4e9f);
    }
}

// =====================================================================
// Kernel 4: greedy NMS (unchanged).
// =====================================================================
__global__ __launch_bounds__(1024) void nms_kernel(
    const float* __restrict__ CSC, const float* __restrict__ CBX,
    const int* __restrict__ CIX, float* __restrict__ out)
{
    const int b = blockIdx.x, tid = threadIdx.x;
    const float*  csc = CSC + (size_t)b * CAND_PAD;
    const float4* cbx = (const float4*)CBX + (size_t)b * CAND_PAD;
    const int*    cix = CIX + (size_t)b * CAND_PAD;

    float sc[6], bx1[6], by1[6], bx2[6], by2[6], ar[6];
    int ix[6];
#pragma unroll
    for (int k = 0; k < 6; k++) {
        int g = tid + (k << 10);
        sc[k] = csc[g];
        float4 v = cbx[g];
        bx1[k] = v.x; by1[k] = v.y; bx2[k] = v.z; by2[k] = v.w;
        ar[k] = (v.z - v.x + 1.f) * (v.w - v.y + 1.f);
        ix[k] = cix[g];
    }

    __shared__ float ws_s[16];
    __shared__ int   ws_i[16];
    __shared__ float s_box[4];
    __shared__ float s_fs;
    __shared__ int   s_fi;

    float* rois = out + (size_t)b * 1500;
    float* oscr = out + 6000 + (size_t)b * 300;
    const int lane = tid & 63, wid = tid >> 6;

    for (int it = 0; it < POST_N; it++) {
        float bs = -3.0e38f; int bi = 0x7fffffff;
#pragma unroll
        for (int k = 0; k < 6; k++) {
            if (sc[k] > bs || (sc[k] == bs && ix[k] < bi)) { bs = sc[k]; bi = ix[k]; }
        }
#pragma unroll
        for (int off = 32; off; off >>= 1) {
            float os = __shfl_down(bs, off);
            int   oi = __shfl_down(bi, off);
            if (os > bs || (os == bs && oi < bi)) { bs = os; bi = oi; }
        }
        if (lane == 0) { ws_s[wid] = bs; ws_i[wid] = bi; }
        __syncthreads();
        if (tid < 64) {
            bs = (tid < 16) ? ws_s[tid] : -3.0e38f;
            bi = (tid < 16) ? ws_i[tid] : 0x7fffffff;
#pragma unroll
            for (int off = 8; off; off >>= 1) {
                float os = __shfl_down(bs, off);
                int   oi = __shfl_down(bi, off);
                if (os > bs || (os == bs && oi < bi)) { bs = os; bi = oi; }
            }
            if (tid == 0) { s_fs = bs; s_fi = bi; }
        }
        __syncthreads();
        const float ps = s_fs; const int pi = s_fi;
#pragma unroll
        for (int k = 0; k < 6; k++) {
            if (ix[k] == pi) {
                s_box[0] = bx1[k]; s_box[1] = by1[k];
                s_box[2] = bx2[k]; s_box[3] = by2[k];
            }
        }
        __syncthreads();
        const float px1 = s_box[0], py1 = s_box[1], px2 = s_box[2], py2 = s_box[3];
        const bool valid = ps > -5.0e9f;
        if (tid == 0) {
            float* r = rois + it * 5;
            r[0] = (float)b;
            r[1] = valid ? px1 : 0.f;
            r[2] = valid ? py1 : 0.f;
            r[3] = valid ? px2 : 0.f;
            r[4] = valid ? py2 : 0.f;
            oscr[it] = valid ? ps : 0.f;
        }
        const float parea = (px2 - px1 + 1.f) * (py2 - py1 + 1.f);
#pragma unroll
        for (int k = 0; k < 6; k++) {
            float xx1 = fmaxf(px1, bx1[k]);
            float yy1 = fmaxf(py1, by1[k]);
            float xx2 = fminf(px2, bx2[k]);
            float yy2 = fminf(py2, by2[k]);
            float iw = fmaxf(xx2 - xx1 + 1.f, 0.f);
            float ih = fmaxf(yy2 - yy1 + 1.f, 0.f);
            float inter = iw * ih;
            float iou = inter / (parea + ar[k] - inter);
            if (iou > 0.7f) sc[k] = NEGV;
        }
    }
}

// =====================================================================
extern "C" void kernel_launch(void* const* d_in, const int* in_sizes, int n_in,
                              void* d_out, int out_size, void* d_ws, size_t ws_size,
                              hipStream_t stream)
{
    const float* base_feat = (const float*)d_in[0];
    const float* im_info   = (const float*)d_in[1];
    const float* conv_w    = (const float*)d_in[4];
    const float* conv_b    = (const float*)d_in[5];
    const float* cls_w     = (const float*)d_in[6];
    const float* cls_b     = (const float*)d_in[7];
    const float* bbox_w    = (const float*)d_in[8];
    const float* bbox_b    = (const float*)d_in[9];

    float* ws  = (float*)d_ws;
    float* X   = ws + X_OFF;
    float* SC  = ws + SC_OFF;
    float* BX  = ws + BX_OFF;
    float* CSC = ws + CSC_OFF;
    float* CBX = ws + CBX_OFF;
    int*   CIX = (int*)(ws + CIX_OFF);
    u16*   WTH = (u16*)(ws + WTH_OFF);
    u16*   WTL = (u16*)(ws + WTL_OFF);
    float* out = (float*)d_out;

    hipLaunchKernelGGL(prep_wtk, dim3(18432), dim3(256), 0, stream,
                       conv_w, WTH, WTL);
    hipLaunchKernelGGL(conv3_mfma, dim3(128, 4), dim3(256), 0, stream,
                       WTH, WTL, base_feat, conv_b, X);
    hipLaunchKernelGGL(heads_kernel, dim3(64), dim3(256), 0, stream,
                       X, cls_w, cls_b, bbox_w, bbox_b, im_info, SC, BX);
    hipLaunchKernelGGL(select_kernel, dim3(4), dim3(1024), 0, stream,
                       SC, BX, CSC, CBX, CIX);
    hipLaunchKernelGGL(nms_kernel, dim3(4), dim3(1024), 0, stream,
                       CSC, CBX, CIX, out);
}

// Round 5
// 1805.166 us; speedup vs baseline: 2.0285x; 1.2109x over previous
//
#include <hip/hip_runtime.h>
#include <stdint.h>

#define HH_ 64
#define WW_ 64
#define NB 4
#define CIN 1024
#define CMID 512
#define NANCH (HH_*WW_*9)      // 36864
#define PRE_N 6000
#define POST_N 300
#define CAND_PAD 6144
#define NEGV (-1.0e10f)
#define LO_SCL 2048.0f         // 2^11
#define LO_INV 4.8828125e-4f   // 2^-11

typedef unsigned short u16;
typedef __attribute__((ext_vector_type(8))) _Float16 f16x8;
typedef __attribute__((ext_vector_type(4))) float f32x4;

#define AS1 __attribute__((address_space(1)))
#define AS3 __attribute__((address_space(3)))

// ---------------- workspace layout (float units) ----------------
// total = 30,769,408 floats = 123.1 MB (validated working in R0/R3 evidence)
#define X_OFF   0
#define X_SZ    (NB*CMID*HH_*WW_)        // 8,388,608
#define SC_OFF  (X_OFF + X_SZ)
#define SC_SZ   (NB*NANCH)               // 147,456
#define BX_OFF  (SC_OFF + SC_SZ)
#define BX_SZ   (NB*NANCH*4)             // 589,824
#define CSC_OFF (BX_OFF + BX_SZ)
#define CSC_SZ  (NB*CAND_PAD)
#define CBX_OFF (CSC_OFF + CSC_SZ)
#define CBX_SZ  (NB*CAND_PAD*4)
#define CIX_OFF (CBX_OFF + CBX_SZ)
#define CIX_SZ  (NB*CAND_PAD)
#define WTH_OFF (CIX_OFF + CIX_SZ)
#define WTH_SZ  (9*512*1024/2)           // fp16 hi weights [r][co][ci_perm]
#define WTL_OFF (WTH_OFF + WTH_SZ)
#define WTL_SZ  WTH_SZ
#define XH_OFF  (WTL_OFF + WTL_SZ)
#define XH_SZ   (NB*4096*1024/2)         // fp16 hi acts NHWC [b][sp][ci_perm]
#define XL_OFF  (XH_OFF + XH_SZ)
#define XL_SZ   XH_SZ
#define ZP_OFF  (XL_OFF + XL_SZ)
#define ZP_SZ   256

// ---------------- helpers ----------------
__device__ __forceinline__ void gl2lds16(const void* g, void* l) {
    __builtin_amdgcn_global_load_lds((const AS1 unsigned int*)g,
                                     (AS3 unsigned int*)l, 16, 0, 0);
}
union fh_u { _Float16 h; u16 u; };
__device__ __forceinline__ u16 f2h_hi(float x) {
    fh_u c; c.h = (_Float16)x; return c.u;
}
__device__ __forceinline__ u16 f2h_lo(float x, u16 hi) {
    fh_u c; c.u = hi;
    float hf = (float)c.h;
    fh_u d; d.h = (_Float16)((x - hf) * LO_SCL);
    return d.u;
}
// slot->channel map within each 32-chunk (matches MFMA per-lane k grouping):
// slot 8h+j holds channel c = (j<4) ? 4h+j : 16+4h+(j-4).
// cperm(c) is the inverse (channel -> slot). Applied identically to A and B,
// so the contraction is invariant to the permutation.
__device__ __forceinline__ int cperm(int c) {
    int blk = c >> 5, w = c & 31;
    int pos = (w < 16) ? (((w >> 2) << 3) + (w & 3))
                       : ((((w - 16) >> 2) << 3) + 4 + (w & 3));
    return (blk << 5) + pos;
}

// =====================================================================
// Prep A: conv weights fp32 [co][ci][3][3] -> fp16 hi / scaled-lo
// [r][co][ci_perm]. w = hi + lo*2^-11. Also zeroes the halo zero-page.
// =====================================================================
__global__ __launch_bounds__(256) void prep_wtk(
    const float* __restrict__ conv_w, u16* __restrict__ WTH,
    u16* __restrict__ WTL, float* __restrict__ ZP)
{
    int o = blockIdx.x * 256 + threadIdx.x;      // < 4,718,592
    int ci = o & 1023, co = (o >> 10) & 511, r = o >> 19;
    float v = conv_w[((size_t)(co * 1024 + ci)) * 9 + r];
    u16 h  = f2h_hi(v);
    u16 lo = f2h_lo(v, h);
    size_t d = (((size_t)(r * 512 + co)) << 10) + cperm(ci);
    WTH[d] = h; WTL[d] = lo;
    if (o < 256) ZP[o] = 0.f;
}

// =====================================================================
// Prep B: activations fp32 NCHW -> fp16 hi/scaled-lo NHWC [b][sp][ci_perm]
// LDS-tiled 64x64 transpose (coalesced both sides).
// =====================================================================
__global__ __launch_bounds__(256) void prep_act(
    const float* __restrict__ in, u16* __restrict__ XH, u16* __restrict__ XL)
{
    __shared__ float T[64][65];
    const int blk = blockIdx.x;                  // 4 * 16 * 64 = 4096
    const int b   = blk >> 10;
    const int ci0 = ((blk >> 6) & 15) << 6;
    const int sp0 = (blk & 63) << 6;
    const int tid = threadIdx.x;
    const int tq  = tid >> 6;                    // 0..3
    const int t64 = tid & 63;
#pragma unroll
    for (int w = 0; w < 16; w++) {
        int ci_l = w * 4 + tq;
        T[ci_l][t64] = in[(((size_t)(b * 1024 + ci0 + ci_l)) << 12) + sp0 + t64];
    }
    __syncthreads();
#pragma unroll
    for (int w = 0; w < 16; w++) {
        int sp_l = w * 4 + tq;
        float x = T[t64][sp_l];
        u16 h  = f2h_hi(x);
        u16 lo = f2h_lo(x, h);
        size_t d = (((size_t)((b << 12) + sp0 + sp_l)) << 10) + ci0 + cperm(t64);
        XH[d] = h; XL[d] = lo;
    }
}

// =====================================================================
// Kernel 1: 3x3 conv as scaled-split-fp16 MFMA implicit GEMM.
// acc0 = Ah*Bh ; acc1 = Ah*Bl + Al*Bh ; C = acc0 + acc1*2^-11.
// M=512(co) N=16384(b,y,x) K=9216. 128x128 tile, BK=32, 256 thr
// (2x2 waves, 4x4 16x16x32_f16 frags), dbuf LDS 64KB.
// A and B both staged via global_load_lds w=16 from pre-split fp16
// arrays (linear [row][32slot] LDS); per-lane zero-page redirect for
// halo taps (global source is per-lane; LDS dest stays linear).
// =====================================================================
__global__ __launch_bounds__(256, 2) void conv3_mfma(
    const u16* __restrict__ WTH, const u16* __restrict__ WTL,
    const u16* __restrict__ XH, const u16* __restrict__ XL,
    const u16* __restrict__ ZP, const float* __restrict__ bias,
    float* __restrict__ Xout)
{
    __shared__ u16 Ah_s[2][4096];
    __shared__ u16 Al_s[2][4096];
    __shared__ u16 Bh_s[2][4096];
    __shared__ u16 Bl_s[2][4096];

    const int tid = threadIdx.x;
    const int bn  = blockIdx.x;              // 0..127
    const int bm  = blockIdx.y;              // 0..3
    const int l   = tid & 63;
    const int wid = tid >> 6, wm = wid >> 1, wn = wid & 1;

    // staging map: row rowq (0..63 per q-half), 16B chunk c8
    const int rowq = tid >> 2;
    const int c8   = (tid & 3) << 3;

    int spb[2]; unsigned vmq[2];
#pragma unroll
    for (int q = 0; q < 2; q++) {
        int n = bn * 128 + q * 64 + rowq;
        int yy = (n >> 6) & 63, xx = n & 63;
        spb[q] = n;                          // (b<<12) + y*64 + x
        unsigned m9 = 0;
#pragma unroll
        for (int rr = 0; rr < 9; rr++) {
            int dy = rr / 3 - 1, dx = rr % 3 - 1;
            if ((unsigned)(yy + dy) < 64u && (unsigned)(xx + dx) < 64u)
                m9 |= 1u << rr;
        }
        vmq[q] = m9;
    }

    f32x4 acc0[4][4], acc1[4][4];
#pragma unroll
    for (int i = 0; i < 4; i++)
#pragma unroll
        for (int j = 0; j < 4; j++) { acc0[i][j] = (f32x4)0.f; acc1[i][j] = (f32x4)0.f; }

    const int NK = 288;                      // 9216/32

    auto stage = [&](int sb, int kt) {
        const int r   = kt >> 5;
        const int ci0 = (kt & 31) << 5;
        const int kr  = (r * 11) >> 5;       // r/3 for r<9
        const int sh  = (kr - 1) * 64 + (r - 3 * kr - 1);
        const size_t wbase = (((size_t)(r * 512 + bm * 128)) << 10) + ci0 + c8;
        u16* ah = &Ah_s[sb][tid * 8];
        u16* al = &Al_s[sb][tid * 8];
        u16* bh = &Bh_s[sb][tid * 8];
        u16* bl = &Bl_s[sb][tid * 8];
#pragma unroll
        for (int q = 0; q < 2; q++) {
            const size_t aoff = wbase + (((size_t)(q * 64 + rowq)) << 10);
            gl2lds16(WTH + aoff, ah + q * 2048);
            gl2lds16(WTL + aoff, al + q * 2048);
            const bool v = (vmq[q] >> r) & 1u;
            const size_t boff = (((size_t)(spb[q] + sh)) << 10) + ci0 + c8;
            gl2lds16(v ? (XH + boff) : ZP, bh + q * 2048);
            gl2lds16(v ? (XL + boff) : ZP, bl + q * 2048);
        }
    };

    stage(0, 0);
    int buf = 0;
    for (int kt = 0; kt < NK; ++kt) {
        __syncthreads();                     // stage(buf) landed; prior reads drained
        if (kt + 1 < NK) stage(buf ^ 1, kt + 1);   // async prefetch overlaps MFMAs
        {
            const int lo16 = l & 15, hi4 = l >> 4;
            const int aoff = (wm * 64 + lo16) * 32 + hi4 * 8;
            const int boff = (wn * 64 + lo16) * 32 + hi4 * 8;
            f16x8 ah[4], av[4], bh[4], bv[4];
#pragma unroll
            for (int i = 0; i < 4; i++) {
                ah[i] = *(const f16x8*)&Ah_s[buf][aoff + i * 512];
                av[i] = *(const f16x8*)&Al_s[buf][aoff + i * 512];
                bh[i] = *(const f16x8*)&Bh_s[buf][boff + i * 512];
                bv[i] = *(const f16x8*)&Bl_s[buf][boff + i * 512];
            }
#pragma unroll
            for (int mi = 0; mi < 4; mi++)
#pragma unroll
                for (int ni = 0; ni < 4; ni++) {
                    acc0[mi][ni] = __builtin_amdgcn_mfma_f32_16x16x32_f16(
                        ah[mi], bh[ni], acc0[mi][ni], 0, 0, 0);
                    acc1[mi][ni] = __builtin_amdgcn_mfma_f32_16x16x32_f16(
                        ah[mi], bv[ni], acc1[mi][ni], 0, 0, 0);
                    acc1[mi][ni] = __builtin_amdgcn_mfma_f32_16x16x32_f16(
                        av[mi], bh[ni], acc1[mi][ni], 0, 0, 0);
                }
        }
        buf ^= 1;
    }

    // epilogue: combine + bias + relu -> X NCHW fp32.
    // C/D map: col(n)=lane&15, row(co)=(lane>>4)*4+reg  [m89/m91-verified]
#pragma unroll
    for (int mi = 0; mi < 4; mi++) {
        const int co0 = bm * 128 + wm * 64 + mi * 16 + ((l >> 4) << 2);
        const f32x4 b4 = *(const f32x4*)&bias[co0];
#pragma unroll
        for (int ni = 0; ni < 4; ni++) {
            const int n = bn * 128 + wn * 64 + ni * 16 + (l & 15);
            const int b = n >> 12, sp = n & 4095;
            f32x4 v0 = acc0[mi][ni], v1 = acc1[mi][ni];
            float* xo = Xout + (((size_t)(b * 512 + co0)) << 12) + sp;
            xo[0]        = fmaxf(fmaf(v1[0], LO_INV, v0[0]) + b4[0], 0.f);
            xo[4096]     = fmaxf(fmaf(v1[1], LO_INV, v0[1]) + b4[1], 0.f);
            xo[2 * 4096] = fmaxf(fmaf(v1[2], LO_INV, v0[2]) + b4[2], 0.f);
            xo[3 * 4096] = fmaxf(fmaf(v1[3], LO_INV, v0[3]) + b4[3], 0.f);
        }
    }
}

// =====================================================================
// Kernel 2: 1x1 heads + softmax + box decode + clip (unchanged).
// =====================================================================
__global__ __launch_bounds__(256) void heads_kernel(
    const float* __restrict__ X, const float* __restrict__ cls_w,
    const float* __restrict__ cls_b, const float* __restrict__ bbox_w,
    const float* __restrict__ bbox_b, const float* __restrict__ im_info,
    float* __restrict__ SC, float* __restrict__ BXo)
{
    __shared__ float Ws[54][64];
    const int tid = threadIdx.x;
    const int blk = blockIdx.x;            // 0..63
    const int b   = blk >> 4;
    const int s   = ((blk & 15) << 8) + tid;

    float acc[54];
#pragma unroll
    for (int j = 0; j < 18; j++) acc[j] = cls_b[j];
#pragma unroll
    for (int j = 0; j < 36; j++) acc[18 + j] = bbox_b[j];

    const float* xp = X + (size_t)b * CMID * 4096 + s;
    for (int c0 = 0; c0 < 512; c0 += 64) {
        __syncthreads();
        for (int e = tid; e < 54 * 64; e += 256) {
            int j = e >> 6, ci = e & 63;
            Ws[j][ci] = (j < 18) ? cls_w[j * 512 + c0 + ci]
                                 : bbox_w[(j - 18) * 512 + c0 + ci];
        }
        __syncthreads();
        for (int ci = 0; ci < 64; ci += 4) {
            float x0 = xp[(size_t)(c0 + ci) * 4096];
            float x1 = xp[(size_t)(c0 + ci + 1) * 4096];
            float x2 = xp[(size_t)(c0 + ci + 2) * 4096];
            float x3 = xp[(size_t)(c0 + ci + 3) * 4096];
#pragma unroll
            for (int j = 0; j < 54; j++) {
                float4 w4 = *(const float4*)&Ws[j][ci];
                acc[j] = fmaf(x3, w4.w, fmaf(x2, w4.z, fmaf(x1, w4.y, fmaf(x0, w4.x, acc[j]))));
            }
        }
    }

    const float imh = im_info[b * 3 + 0];
    const float imw = im_info[b * 3 + 1];
    const int hh = s >> 6, ww = s & 63;
    const float cxa = 7.5f + 16.f * (float)ww;
    const float cya = 7.5f + 16.f * (float)hh;
    const float WA[9] = {184.f, 368.f, 736.f, 128.f, 256.f, 512.f, 88.f, 176.f, 352.f};
    const float HA[9] = {96.f, 192.f, 384.f, 128.f, 256.f, 512.f, 176.f, 352.f, 704.f};
    const size_t base = (size_t)b * NANCH + (size_t)s * 9;
#pragma unroll
    for (int c = 0; c < 9; c++) {
        float bg = acc[c], fg = acc[9 + c];
        float m  = fmaxf(bg, fg);
        float e0 = expf(bg - m), e1 = expf(fg - m);
        float p  = e1 / (e0 + e1);
        float dx = acc[18 + 4 * c], dy = acc[19 + 4 * c];
        float dw = acc[20 + 4 * c], dh = acc[21 + 4 * c];
        float wa = WA[c], ha = HA[c];
        float cx = dx * wa + cxa;
        float cy = dy * ha + cya;
        float pw = expf(dw) * wa;
        float ph = expf(dh) * ha;
        float x1 = cx - 0.5f * pw, y1 = cy - 0.5f * ph;
        float x2 = cx + 0.5f * pw, y2 = cy + 0.5f * ph;
        x1 = fminf(fmaxf(x1, 0.f), imw - 1.f);
        y1 = fminf(fmaxf(y1, 0.f), imh - 1.f);
        x2 = fminf(fmaxf(x2, 0.f), imw - 1.f);
        y2 = fminf(fmaxf(y2, 0.f), imh - 1.f);
        SC[base + c] = p;
        *(float4*)&BXo[(base + c) * 4] = make_float4(x1, y1, x2, y2);
    }
}

// =====================================================================
// Kernel 3: per-batch exact top-6000 selection (unchanged).
// =====================================================================
__global__ __launch_bounds__(1024) void select_kernel(
    const float* __restrict__ SC, const float* __restrict__ BX,
    float* __restrict__ CSC, float* __restrict__ CBX, int* __restrict__ CIX)
{
    const int b = blockIdx.x, tid = threadIdx.x;
    const float* sc = SC + (size_t)b * NANCH;
    const unsigned* bits = (const unsigned*)sc;
    __shared__ int s_cnt;
    __shared__ int s_c1, s_c2;
    __shared__ int s_tie[8192];

    unsigned lo = 0u, hi = 0x3f800001u;
    while (hi - lo > 1u) {
        unsigned mid = lo + ((hi - lo) >> 1);
        if (tid == 0) s_cnt = 0;
        __syncthreads();
        int c = 0;
        for (int i = tid; i < NANCH; i += 1024) c += (bits[i] >= mid) ? 1 : 0;
#pragma unroll
        for (int off = 32; off; off >>= 1) c += __shfl_down(c, off);
        if ((tid & 63) == 0) atomicAdd(&s_cnt, c);
        __syncthreads();
        int total = s_cnt;
        __syncthreads();
        if (total >= PRE_N) lo = mid; else hi = mid;
    }
    const unsigned ustar = lo;

    if (tid == 0) s_cnt = 0;
    __syncthreads();
    {
        int c = 0;
        for (int i = tid; i < NANCH; i += 1024) c += (bits[i] > ustar) ? 1 : 0;
#pragma unroll
        for (int off = 32; off; off >>= 1) c += __shfl_down(c, off);
        if ((tid & 63) == 0) atomicAdd(&s_cnt, c);
    }
    __syncthreads();
    const int n1 = s_cnt;
    __syncthreads();

    if (tid == 0) { s_c1 = 0; s_c2 = 0; }
    __syncthreads();

    const float4* bx4 = (const float4*)BX + (size_t)b * NANCH;
    float4* cbx4 = (float4*)CBX + (size_t)b * CAND_PAD;
    float*  csc  = CSC + (size_t)b * CAND_PAD;
    int*    cix  = CIX + (size_t)b * CAND_PAD;

    for (int i = tid; i < NANCH; i += 1024) {
        unsigned u = bits[i];
        if (u > ustar) {
            int p = atomicAdd(&s_c1, 1);
            csc[p] = sc[i]; cbx4[p] = bx4[i]; cix[p] = i;
        } else if (u == ustar) {
            int p = atomicAdd(&s_c2, 1);
            if (p < 8192) s_tie[p] = i;
        }
    }
    __syncthreads();
    int m = s_c2; if (m > 8192) m = 8192;
    const int need = PRE_N - n1;
    for (int i = tid; i < 8192; i += 1024)
        if (i >= m) s_tie[i] = 0x7fffffff;
    __syncthreads();

    for (int k = 2; k <= 8192; k <<= 1) {
        for (int j = k >> 1; j > 0; j >>= 1) {
            for (int t = tid; t < 8192; t += 1024) {
                int ixj = t ^ j;
                if (ixj > t) {
                    int va = s_tie[t], vb = s_tie[ixj];
                    bool up = ((t & k) == 0);
                    if ((va > vb) == up) { s_tie[t] = vb; s_tie[ixj] = va; }
                }
            }
            __syncthreads();
        }
    }
    for (int t = tid; t < need; t += 1024) {
        int i = s_tie[t];
        int p = n1 + t;
        if (i >= 0 && i < NANCH) {
            csc[p] = sc[i]; cbx4[p] = bx4[i]; cix[p] = i;
        } else {
            csc[p] = -2.0e10f; cix[p] = 0x7fffffff;
            cbx4[p] = make_float4(-4e9f, -4e9f, -4e9f, -4e9f);
        }
    }
    for (int p = PRE_N + tid; p < CAND_PAD; p += 1024) {
        csc[p] = -2.0e10f;
        cix[p] = 0x7fffffff;
        cbx4[p] = make_float4(-4e9f, -4e9f, -4e9f, -4e9f);
    }
}

// =====================================================================
// Kernel 4: greedy NMS (unchanged).
// =====================================================================
__global__ __launch_bounds__(1024) void nms_kernel(
    const float* __restrict__ CSC, const float* __restrict__ CBX,
    const int* __restrict__ CIX, float* __restrict__ out)
{
    const int b = blockIdx.x, tid = threadIdx.x;
    const float*  csc = CSC + (size_t)b * CAND_PAD;
    const float4* cbx = (const float4*)CBX + (size_t)b * CAND_PAD;
    const int*    cix = CIX + (size_t)b * CAND_PAD;

    float sc[6], bx1[6], by1[6], bx2[6], by2[6], ar[6];
    int ix[6];
#pragma unroll
    for (int k = 0; k < 6; k++) {
        int g = tid + (k << 10);
        sc[k] = csc[g];
        float4 v = cbx[g];
        bx1[k] = v.x; by1[k] = v.y; bx2[k] = v.z; by2[k] = v.w;
        ar[k] = (v.z - v.x + 1.f) * (v.w - v.y + 1.f);
        ix[k] = cix[g];
    }

    __shared__ float ws_s[16];
    __shared__ int   ws_i[16];
    __shared__ float s_box[4];
    __shared__ float s_fs;
    __shared__ int   s_fi;

    float* rois = out + (size_t)b * 1500;
    float* oscr = out + 6000 + (size_t)b * 300;
    const int lane = tid & 63, wid = tid >> 6;

    for (int it = 0; it < POST_N; it++) {
        float bs = -3.0e38f; int bi = 0x7fffffff;
#pragma unroll
        for (int k = 0; k < 6; k++) {
            if (sc[k] > bs || (sc[k] == bs && ix[k] < bi)) { bs = sc[k]; bi = ix[k]; }
        }
#pragma unroll
        for (int off = 32; off; off >>= 1) {
            float os = __shfl_down(bs, off);
            int   oi = __shfl_down(bi, off);
            if (os > bs || (os == bs && oi < bi)) { bs = os; bi = oi; }
        }
        if (lane == 0) { ws_s[wid] = bs; ws_i[wid] = bi; }
        __syncthreads();
        if (tid < 64) {
            bs = (tid < 16) ? ws_s[tid] : -3.0e38f;
            bi = (tid < 16) ? ws_i[tid] : 0x7fffffff;
#pragma unroll
            for (int off = 8; off; off >>= 1) {
                float os = __shfl_down(bs, off);
                int   oi = __shfl_down(bi, off);
                if (os > bs || (os == bs && oi < bi)) { bs = os; bi = oi; }
            }
            if (tid == 0) { s_fs = bs; s_fi = bi; }
        }
        __syncthreads();
        const float ps = s_fs; const int pi = s_fi;
#pragma unroll
        for (int k = 0; k < 6; k++) {
            if (ix[k] == pi) {
                s_box[0] = bx1[k]; s_box[1] = by1[k];
                s_box[2] = bx2[k]; s_box[3] = by2[k];
            }
        }
        __syncthreads();
        const float px1 = s_box[0], py1 = s_box[1], px2 = s_box[2], py2 = s_box[3];
        const bool valid = ps > -5.0e9f;
        if (tid == 0) {
            float* r = rois + it * 5;
            r[0] = (float)b;
            r[1] = valid ? px1 : 0.f;
            r[2] = valid ? py1 : 0.f;
            r[3] = valid ? px2 : 0.f;
            r[4] = valid ? py2 : 0.f;
            oscr[it] = valid ? ps : 0.f;
        }
        const float parea = (px2 - px1 + 1.f) * (py2 - py1 + 1.f);
#pragma unroll
        for (int k = 0; k < 6; k++) {
            float xx1 = fmaxf(px1, bx1[k]);
            float yy1 = fmaxf(py1, by1[k]);
            float xx2 = fminf(px2, bx2[k]);
            float yy2 = fminf(py2, by2[k]);
            float iw = fmaxf(xx2 - xx1 + 1.f, 0.f);
            float ih = fmaxf(yy2 - yy1 + 1.f, 0.f);
            float inter = iw * ih;
            float iou = inter / (parea + ar[k] - inter);
            if (iou > 0.7f) sc[k] = NEGV;
        }
    }
}

// =====================================================================
extern "C" void kernel_launch(void* const* d_in, const int* in_sizes, int n_in,
                              void* d_out, int out_size, void* d_ws, size_t ws_size,
                              hipStream_t stream)
{
    const float* base_feat = (const float*)d_in[0];
    const float* im_info   = (const float*)d_in[1];
    const float* conv_w    = (const float*)d_in[4];
    const float* conv_b    = (const float*)d_in[5];
    const float* cls_w     = (const float*)d_in[6];
    const float* cls_b     = (const float*)d_in[7];
    const float* bbox_w    = (const float*)d_in[8];
    const float* bbox_b    = (const float*)d_in[9];

    float* ws  = (float*)d_ws;
    float* X   = ws + X_OFF;
    float* SC  = ws + SC_OFF;
    float* BX  = ws + BX_OFF;
    float* CSC = ws + CSC_OFF;
    float* CBX = ws + CBX_OFF;
    int*   CIX = (int*)(ws + CIX_OFF);
    u16*   WTH = (u16*)(ws + WTH_OFF);
    u16*   WTL = (u16*)(ws + WTL_OFF);
    u16*   XHp = (u16*)(ws + XH_OFF);
    u16*   XLp = (u16*)(ws + XL_OFF);
    float* ZPf = ws + ZP_OFF;
    const u16* ZPu = (const u16*)ZPf;
    float* out = (float*)d_out;

    hipLaunchKernelGGL(prep_wtk, dim3(18432), dim3(256), 0, stream,
                       conv_w, WTH, WTL, ZPf);
    hipLaunchKernelGGL(prep_act, dim3(4096), dim3(256), 0, stream,
                       base_feat, XHp, XLp);
    hipLaunchKernelGGL(conv3_mfma, dim3(128, 4), dim3(256), 0, stream,
                       WTH, WTL, XHp, XLp, ZPu, conv_b, X);
    hipLaunchKernelGGL(heads_kernel, dim3(64), dim3(256), 0, stream,
                       X, cls_w, cls_b, bbox_w, bbox_b, im_info, SC, BX);
    hipLaunchKernelGGL(select_kernel, dim3(4), dim3(1024), 0, stream,
                       SC, BX, CSC, CBX, CIX);
    hipLaunchKernelGGL(nms_kernel, dim3(4), dim3(1024), 0, stream,
                       CSC, CBX, CIX, out);
}

// Round 6
// 1771.524 us; speedup vs baseline: 2.0670x; 1.0190x over previous
//
#include <hip/hip_runtime.h>
#include <stdint.h>

#define HH_ 64
#define WW_ 64
#define NB 4
#define CIN 1024
#define CMID 512
#define NANCH (HH_*WW_*9)      // 36864
#define PRE_N 6000
#define POST_N 300
#define CAND_PAD 6144
#define NEGV (-1.0e10f)
#define LO_SCL 2048.0f         // 2^11
#define LO_INV 4.8828125e-4f   // 2^-11

typedef unsigned short u16;
typedef __attribute__((ext_vector_type(8))) _Float16 f16x8;
typedef __attribute__((ext_vector_type(4))) float f32x4;

#define AS1 __attribute__((address_space(1)))
#define AS3 __attribute__((address_space(3)))

// ---------------- workspace layout (float units) ----------------
// total = 30,769,408 floats = 123.1 MB (validated working)
#define X_OFF   0
#define X_SZ    (NB*CMID*HH_*WW_)        // 8,388,608
#define SC_OFF  (X_OFF + X_SZ)
#define SC_SZ   (NB*NANCH)               // 147,456
#define BX_OFF  (SC_OFF + SC_SZ)
#define BX_SZ   (NB*NANCH*4)             // 589,824
#define CSC_OFF (BX_OFF + BX_SZ)
#define CSC_SZ  (NB*CAND_PAD)
#define CBX_OFF (CSC_OFF + CSC_SZ)
#define CBX_SZ  (NB*CAND_PAD*4)
#define CIX_OFF (CBX_OFF + CBX_SZ)
#define CIX_SZ  (NB*CAND_PAD)
#define WTH_OFF (CIX_OFF + CIX_SZ)
#define WTH_SZ  (9*512*1024/2)           // fp16 hi weights [r][co][ci_perm]
#define WTL_OFF (WTH_OFF + WTH_SZ)
#define WTL_SZ  WTH_SZ
#define XH_OFF  (WTL_OFF + WTL_SZ)
#define XH_SZ   (NB*4096*1024/2)         // fp16 hi acts NHWC [b][sp][ci_perm]
#define XL_OFF  (XH_OFF + XH_SZ)
#define XL_SZ   XH_SZ
#define ZP_OFF  (XL_OFF + XL_SZ)
#define ZP_SZ   256

// ---------------- helpers ----------------
__device__ __forceinline__ void gl2lds16(const void* g, void* l) {
    __builtin_amdgcn_global_load_lds((const AS1 unsigned int*)g,
                                     (AS3 unsigned int*)l, 16, 0, 0);
}
union fh_u { _Float16 h; u16 u; };
__device__ __forceinline__ u16 f2h_hi(float x) {
    fh_u c; c.h = (_Float16)x; return c.u;
}
__device__ __forceinline__ u16 f2h_lo(float x, u16 hi) {
    fh_u c; c.u = hi;
    float hf = (float)c.h;
    fh_u d; d.h = (_Float16)((x - hf) * LO_SCL);
    return d.u;
}
// slot->channel map within each 32-chunk (matches MFMA per-lane k grouping):
// slot 8h+j holds channel c = (j<4) ? 4h+j : 16+4h+(j-4).
// cperm(c) is the inverse (channel -> slot). Applied identically to A and B,
// so the contraction is invariant to the permutation.
__device__ __forceinline__ int cperm(int c) {
    int blk = c >> 5, w = c & 31;
    int pos = (w < 16) ? (((w >> 2) << 3) + (w & 3))
                       : ((((w - 16) >> 2) << 3) + 4 + (w & 3));
    return (blk << 5) + pos;
}
// order-preserving float->u32 (monotonic for all finite floats)
__device__ __forceinline__ unsigned fflip(unsigned u) {
    return (u & 0x80000000u) ? ~u : (u | 0x80000000u);
}

// =====================================================================
// Prep A: conv weights fp32 [co][ci][3][3] -> fp16 hi / scaled-lo
// [r][co][ci_perm]. w = hi + lo*2^-11. Also zeroes the halo zero-page.
// =====================================================================
__global__ __launch_bounds__(256) void prep_wtk(
    const float* __restrict__ conv_w, u16* __restrict__ WTH,
    u16* __restrict__ WTL, float* __restrict__ ZP)
{
    int o = blockIdx.x * 256 + threadIdx.x;      // < 4,718,592
    int ci = o & 1023, co = (o >> 10) & 511, r = o >> 19;
    float v = conv_w[((size_t)(co * 1024 + ci)) * 9 + r];
    u16 h  = f2h_hi(v);
    u16 lo = f2h_lo(v, h);
    size_t d = (((size_t)(r * 512 + co)) << 10) + cperm(ci);
    WTH[d] = h; WTL[d] = lo;
    if (o < 256) ZP[o] = 0.f;
}

// =====================================================================
// Prep B: activations fp32 NCHW -> fp16 hi/scaled-lo NHWC [b][sp][ci_perm]
// LDS-tiled 64x64 transpose (coalesced both sides).
// =====================================================================
__global__ __launch_bounds__(256) void prep_act(
    const float* __restrict__ in, u16* __restrict__ XH, u16* __restrict__ XL)
{
    __shared__ float T[64][65];
    const int blk = blockIdx.x;                  // 4 * 16 * 64 = 4096
    const int b   = blk >> 10;
    const int ci0 = ((blk >> 6) & 15) << 6;
    const int sp0 = (blk & 63) << 6;
    const int tid = threadIdx.x;
    const int tq  = tid >> 6;                    // 0..3
    const int t64 = tid & 63;
#pragma unroll
    for (int w = 0; w < 16; w++) {
        int ci_l = w * 4 + tq;
        T[ci_l][t64] = in[(((size_t)(b * 1024 + ci0 + ci_l)) << 12) + sp0 + t64];
    }
    __syncthreads();
#pragma unroll
    for (int w = 0; w < 16; w++) {
        int sp_l = w * 4 + tq;
        float x = T[t64][sp_l];
        u16 h  = f2h_hi(x);
        u16 lo = f2h_lo(x, h);
        size_t d = (((size_t)((b << 12) + sp0 + sp_l)) << 10) + ci0 + cperm(t64);
        XH[d] = h; XL[d] = lo;
    }
}

// =====================================================================
// Kernel 1: 3x3 conv as scaled-split-fp16 MFMA implicit GEMM.
// acc0 = Ah*Bh ; acc1 = Ah*Bl + Al*Bh ; C = acc0 + acc1*2^-11.
// M=512(co) N=16384(b,y,x) K=9216. 128x128 tile, BK=32, 256 thr
// (2x2 waves, 4x4 16x16x32_f16 frags), dbuf LDS 64KB.
// A and B both staged via global_load_lds w=16 from pre-split fp16
// arrays; per-lane zero-page redirect for halo taps.
// =====================================================================
__global__ __launch_bounds__(256, 2) void conv3_mfma(
    const u16* __restrict__ WTH, const u16* __restrict__ WTL,
    const u16* __restrict__ XH, const u16* __restrict__ XL,
    const u16* __restrict__ ZP, const float* __restrict__ bias,
    float* __restrict__ Xout)
{
    __shared__ u16 Ah_s[2][4096];
    __shared__ u16 Al_s[2][4096];
    __shared__ u16 Bh_s[2][4096];
    __shared__ u16 Bl_s[2][4096];

    const int tid = threadIdx.x;
    const int bn  = blockIdx.x;              // 0..127
    const int bm  = blockIdx.y;              // 0..3
    const int l   = tid & 63;
    const int wid = tid >> 6, wm = wid >> 1, wn = wid & 1;

    // staging map: row rowq (0..63 per q-half), 16B chunk c8
    const int rowq = tid >> 2;
    const int c8   = (tid & 3) << 3;

    int spb[2]; unsigned vmq[2];
#pragma unroll
    for (int q = 0; q < 2; q++) {
        int n = bn * 128 + q * 64 + rowq;
        int yy = (n >> 6) & 63, xx = n & 63;
        spb[q] = n;                          // (b<<12) + y*64 + x
        unsigned m9 = 0;
#pragma unroll
        for (int rr = 0; rr < 9; rr++) {
            int dy = rr / 3 - 1, dx = rr % 3 - 1;
            if ((unsigned)(yy + dy) < 64u && (unsigned)(xx + dx) < 64u)
                m9 |= 1u << rr;
        }
        vmq[q] = m9;
    }

    f32x4 acc0[4][4], acc1[4][4];
#pragma unroll
    for (int i = 0; i < 4; i++)
#pragma unroll
        for (int j = 0; j < 4; j++) { acc0[i][j] = (f32x4)0.f; acc1[i][j] = (f32x4)0.f; }

    const int NK = 288;                      // 9216/32

    auto stage = [&](int sb, int kt) {
        const int r   = kt >> 5;
        const int ci0 = (kt & 31) << 5;
        const int kr  = (r * 11) >> 5;       // r/3 for r<9
        const int sh  = (kr - 1) * 64 + (r - 3 * kr - 1);
        const size_t wbase = (((size_t)(r * 512 + bm * 128)) << 10) + ci0 + c8;
        u16* ah = &Ah_s[sb][tid * 8];
        u16* al = &Al_s[sb][tid * 8];
        u16* bh = &Bh_s[sb][tid * 8];
        u16* bl = &Bl_s[sb][tid * 8];
#pragma unroll
        for (int q = 0; q < 2; q++) {
            const size_t aoff = wbase + (((size_t)(q * 64 + rowq)) << 10);
            gl2lds16(WTH + aoff, ah + q * 2048);
            gl2lds16(WTL + aoff, al + q * 2048);
            const bool v = (vmq[q] >> r) & 1u;
            const size_t boff = (((size_t)(spb[q] + sh)) << 10) + ci0 + c8;
            gl2lds16(v ? (XH + boff) : ZP, bh + q * 2048);
            gl2lds16(v ? (XL + boff) : ZP, bl + q * 2048);
        }
    };

    stage(0, 0);
    int buf = 0;
    for (int kt = 0; kt < NK; ++kt) {
        __syncthreads();                     // stage(buf) landed; prior reads drained
        if (kt + 1 < NK) stage(buf ^ 1, kt + 1);   // async prefetch overlaps MFMAs
        {
            const int lo16 = l & 15, hi4 = l >> 4;
            const int aoff = (wm * 64 + lo16) * 32 + hi4 * 8;
            const int boff = (wn * 64 + lo16) * 32 + hi4 * 8;
            f16x8 ah[4], av[4], bh[4], bv[4];
#pragma unroll
            for (int i = 0; i < 4; i++) {
                ah[i] = *(const f16x8*)&Ah_s[buf][aoff + i * 512];
                av[i] = *(const f16x8*)&Al_s[buf][aoff + i * 512];
                bh[i] = *(const f16x8*)&Bh_s[buf][boff + i * 512];
                bv[i] = *(const f16x8*)&Bl_s[buf][boff + i * 512];
            }
#pragma unroll
            for (int mi = 0; mi < 4; mi++)
#pragma unroll
                for (int ni = 0; ni < 4; ni++) {
                    acc0[mi][ni] = __builtin_amdgcn_mfma_f32_16x16x32_f16(
                        ah[mi], bh[ni], acc0[mi][ni], 0, 0, 0);
                    acc1[mi][ni] = __builtin_amdgcn_mfma_f32_16x16x32_f16(
                        ah[mi], bv[ni], acc1[mi][ni], 0, 0, 0);
                    acc1[mi][ni] = __builtin_amdgcn_mfma_f32_16x16x32_f16(
                        av[mi], bh[ni], acc1[mi][ni], 0, 0, 0);
                }
        }
        buf ^= 1;
    }

    // epilogue: combine + bias + relu -> X NCHW fp32.
    // C/D map: col(n)=lane&15, row(co)=(lane>>4)*4+reg  [m89/m91-verified]
#pragma unroll
    for (int mi = 0; mi < 4; mi++) {
        const int co0 = bm * 128 + wm * 64 + mi * 16 + ((l >> 4) << 2);
        const f32x4 b4 = *(const f32x4*)&bias[co0];
#pragma unroll
        for (int ni = 0; ni < 4; ni++) {
            const int n = bn * 128 + wn * 64 + ni * 16 + (l & 15);
            const int b = n >> 12, sp = n & 4095;
            f32x4 v0 = acc0[mi][ni], v1 = acc1[mi][ni];
            float* xo = Xout + (((size_t)(b * 512 + co0)) << 12) + sp;
            xo[0]        = fmaxf(fmaf(v1[0], LO_INV, v0[0]) + b4[0], 0.f);
            xo[4096]     = fmaxf(fmaf(v1[1], LO_INV, v0[1]) + b4[1], 0.f);
            xo[2 * 4096] = fmaxf(fmaf(v1[2], LO_INV, v0[2]) + b4[2], 0.f);
            xo[3 * 4096] = fmaxf(fmaf(v1[3], LO_INV, v0[3]) + b4[3], 0.f);
        }
    }
}

// =====================================================================
// Kernel 2: 1x1 heads + softmax + box decode + clip (unchanged).
// =====================================================================
__global__ __launch_bounds__(256) void heads_kernel(
    const float* __restrict__ X, const float* __restrict__ cls_w,
    const float* __restrict__ cls_b, const float* __restrict__ bbox_w,
    const float* __restrict__ bbox_b, const float* __restrict__ im_info,
    float* __restrict__ SC, float* __restrict__ BXo)
{
    __shared__ float Ws[54][64];
    const int tid = threadIdx.x;
    const int blk = blockIdx.x;            // 0..63
    const int b   = blk >> 4;
    const int s   = ((blk & 15) << 8) + tid;

    float acc[54];
#pragma unroll
    for (int j = 0; j < 18; j++) acc[j] = cls_b[j];
#pragma unroll
    for (int j = 0; j < 36; j++) acc[18 + j] = bbox_b[j];

    const float* xp = X + (size_t)b * CMID * 4096 + s;
    for (int c0 = 0; c0 < 512; c0 += 64) {
        __syncthreads();
        for (int e = tid; e < 54 * 64; e += 256) {
            int j = e >> 6, ci = e & 63;
            Ws[j][ci] = (j < 18) ? cls_w[j * 512 + c0 + ci]
                                 : bbox_w[(j - 18) * 512 + c0 + ci];
        }
        __syncthreads();
        for (int ci = 0; ci < 64; ci += 4) {
            float x0 = xp[(size_t)(c0 + ci) * 4096];
            float x1 = xp[(size_t)(c0 + ci + 1) * 4096];
            float x2 = xp[(size_t)(c0 + ci + 2) * 4096];
            float x3 = xp[(size_t)(c0 + ci + 3) * 4096];
#pragma unroll
            for (int j = 0; j < 54; j++) {
                float4 w4 = *(const float4*)&Ws[j][ci];
                acc[j] = fmaf(x3, w4.w, fmaf(x2, w4.z, fmaf(x1, w4.y, fmaf(x0, w4.x, acc[j]))));
            }
        }
    }

    const float imh = im_info[b * 3 + 0];
    const float imw = im_info[b * 3 + 1];
    const int hh = s >> 6, ww = s & 63;
    const float cxa = 7.5f + 16.f * (float)ww;
    const float cya = 7.5f + 16.f * (float)hh;
    const float WA[9] = {184.f, 368.f, 736.f, 128.f, 256.f, 512.f, 88.f, 176.f, 352.f};
    const float HA[9] = {96.f, 192.f, 384.f, 128.f, 256.f, 512.f, 176.f, 352.f, 704.f};
    const size_t base = (size_t)b * NANCH + (size_t)s * 9;
#pragma unroll
    for (int c = 0; c < 9; c++) {
        float bg = acc[c], fg = acc[9 + c];
        float m  = fmaxf(bg, fg);
        float e0 = expf(bg - m), e1 = expf(fg - m);
        float p  = e1 / (e0 + e1);
        float dx = acc[18 + 4 * c], dy = acc[19 + 4 * c];
        float dw = acc[20 + 4 * c], dh = acc[21 + 4 * c];
        float wa = WA[c], ha = HA[c];
        float cx = dx * wa + cxa;
        float cy = dy * ha + cya;
        float pw = expf(dw) * wa;
        float ph = expf(dh) * ha;
        float x1 = cx - 0.5f * pw, y1 = cy - 0.5f * ph;
        float x2 = cx + 0.5f * pw, y2 = cy + 0.5f * ph;
        x1 = fminf(fmaxf(x1, 0.f), imw - 1.f);
        y1 = fminf(fmaxf(y1, 0.f), imh - 1.f);
        x2 = fminf(fmaxf(x2, 0.f), imw - 1.f);
        y2 = fminf(fmaxf(y2, 0.f), imh - 1.f);
        SC[base + c] = p;
        *(float4*)&BXo[(base + c) * 4] = make_float4(x1, y1, x2, y2);
    }
}

// =====================================================================
// Kernel 3: per-batch exact top-6000 selection (unchanged).
// =====================================================================
__global__ __launch_bounds__(1024) void select_kernel(
    const float* __restrict__ SC, const float* __restrict__ BX,
    float* __restrict__ CSC, float* __restrict__ CBX, int* __restrict__ CIX)
{
    const int b = blockIdx.x, tid = threadIdx.x;
    const float* sc = SC + (size_t)b * NANCH;
    const unsigned* bits = (const unsigned*)sc;
    __shared__ int s_cnt;
    __shared__ int s_c1, s_c2;
    __shared__ int s_tie[8192];

    unsigned lo = 0u, hi = 0x3f800001u;
    while (hi - lo > 1u) {
        unsigned mid = lo + ((hi - lo) >> 1);
        if (tid == 0) s_cnt = 0;
        __syncthreads();
        int c = 0;
        for (int i = tid; i < NANCH; i += 1024) c += (bits[i] >= mid) ? 1 : 0;
#pragma unroll
        for (int off = 32; off; off >>= 1) c += __shfl_down(c, off);
        if ((tid & 63) == 0) atomicAdd(&s_cnt, c);
        __syncthreads();
        int total = s_cnt;
        __syncthreads();
        if (total >= PRE_N) lo = mid; else hi = mid;
    }
    const unsigned ustar = lo;

    if (tid == 0) s_cnt = 0;
    __syncthreads();
    {
        int c = 0;
        for (int i = tid; i < NANCH; i += 1024) c += (bits[i] > ustar) ? 1 : 0;
#pragma unroll
        for (int off = 32; off; off >>= 1) c += __shfl_down(c, off);
        if ((tid & 63) == 0) atomicAdd(&s_cnt, c);
    }
    __syncthreads();
    const int n1 = s_cnt;
    __syncthreads();

    if (tid == 0) { s_c1 = 0; s_c2 = 0; }
    __syncthreads();

    const float4* bx4 = (const float4*)BX + (size_t)b * NANCH;
    float4* cbx4 = (float4*)CBX + (size_t)b * CAND_PAD;
    float*  csc  = CSC + (size_t)b * CAND_PAD;
    int*    cix  = CIX + (size_t)b * CAND_PAD;

    for (int i = tid; i < NANCH; i += 1024) {
        unsigned u = bits[i];
        if (u > ustar) {
            int p = atomicAdd(&s_c1, 1);
            csc[p] = sc[i]; cbx4[p] = bx4[i]; cix[p] = i;
        } else if (u == ustar) {
            int p = atomicAdd(&s_c2, 1);
            if (p < 8192) s_tie[p] = i;
        }
    }
    __syncthreads();
    int m = s_c2; if (m > 8192) m = 8192;
    const int need = PRE_N - n1;
    for (int i = tid; i < 8192; i += 1024)
        if (i >= m) s_tie[i] = 0x7fffffff;
    __syncthreads();

    for (int k = 2; k <= 8192; k <<= 1) {
        for (int j = k >> 1; j > 0; j >>= 1) {
            for (int t = tid; t < 8192; t += 1024) {
                int ixj = t ^ j;
                if (ixj > t) {
                    int va = s_tie[t], vb = s_tie[ixj];
                    bool up = ((t & k) == 0);
                    if ((va > vb) == up) { s_tie[t] = vb; s_tie[ixj] = va; }
                }
            }
            __syncthreads();
        }
    }
    for (int t = tid; t < need; t += 1024) {
        int i = s_tie[t];
        int p = n1 + t;
        if (i >= 0 && i < NANCH) {
            csc[p] = sc[i]; cbx4[p] = bx4[i]; cix[p] = i;
        } else {
            csc[p] = -2.0e10f; cix[p] = 0x7fffffff;
            cbx4[p] = make_float4(-4e9f, -4e9f, -4e9f, -4e9f);
        }
    }
    for (int p = PRE_N + tid; p < CAND_PAD; p += 1024) {
        csc[p] = -2.0e10f;
        cix[p] = 0x7fffffff;
        cbx4[p] = make_float4(-4e9f, -4e9f, -4e9f, -4e9f);
    }
}

// =====================================================================
// Kernel 4: greedy NMS, latency-optimized.
// 256 thr (4 waves) x 24 candidates. Keys packed (flip(score), ~cix):
// one 2-word compare does argmax + reference tie-break (score desc,
// anchor idx asc). Suppression = overwrite key hi-word with flip(NEGV).
// One 4-wave barrier per iteration (parity-alternated LDS slots);
// winner box fetched by ALL threads directly from BX[cix] (uniform
// broadcast load) -- no owner-match, no extra barriers.
// IoU expressions identical to the proven kernel (bit-stable decisions).
// =====================================================================
__global__ __launch_bounds__(256, 1) void nms_kernel(
    const float* __restrict__ CSC, const float* __restrict__ CBX,
    const int* __restrict__ CIX, const float* __restrict__ BX,
    float* __restrict__ out)
{
    const int b = blockIdx.x, tid = threadIdx.x;
    const float*  csc = CSC + (size_t)b * CAND_PAD;
    const float4* cbx = (const float4*)CBX + (size_t)b * CAND_PAD;
    const int*    cix = CIX + (size_t)b * CAND_PAD;
    const float4* bxg = (const float4*)BX + (size_t)b * NANCH;

    unsigned khi[24], klo[24];
    float bx1[24], by1[24], bx2[24], by2[24], ar[24];
#pragma unroll
    for (int k = 0; k < 24; k++) {
        int g = tid + (k << 8);
        khi[k] = fflip(__float_as_uint(csc[g]));
        klo[k] = ~((unsigned)cix[g]);
        float4 v = cbx[g];
        bx1[k] = v.x; by1[k] = v.y; bx2[k] = v.z; by2[k] = v.w;
        ar[k] = (v.z - v.x + 1.f) * (v.w - v.y + 1.f);
    }

    const unsigned DEADHI = fflip(__float_as_uint(NEGV));
    __shared__ unsigned s_hi[2][4], s_lo[2][4];
    float* rois = out + (size_t)b * 1500;
    float* oscr = out + 6000 + (size_t)b * 300;
    const int lane = tid & 63, wid = tid >> 6;

    for (int it = 0; it < POST_N; it++) {
        const int par = it & 1;
        // local argmax over 24 (key compare includes tie-break)
        unsigned mhi = khi[0], mlo = klo[0];
#pragma unroll
        for (int k = 1; k < 24; k++) {
            bool gt = (khi[k] > mhi) || (khi[k] == mhi && klo[k] > mlo);
            mhi = gt ? khi[k] : mhi;
            mlo = gt ? klo[k] : mlo;
        }
        // wave reduce
#pragma unroll
        for (int off = 32; off; off >>= 1) {
            unsigned ohi = __shfl_down(mhi, off);
            unsigned olo = __shfl_down(mlo, off);
            bool gt = (ohi > mhi) || (ohi == mhi && olo > mlo);
            mhi = gt ? ohi : mhi;
            mlo = gt ? olo : mlo;
        }
        if (lane == 0) { s_hi[par][wid] = mhi; s_lo[par][wid] = mlo; }
        __syncthreads();
        // final 4-way (all threads)
        unsigned fhi = s_hi[par][0], flo = s_lo[par][0];
#pragma unroll
        for (int w = 1; w < 4; w++) {
            unsigned ohi = s_hi[par][w], olo = s_lo[par][w];
            bool gt = (ohi > fhi) || (ohi == fhi && olo > flo);
            fhi = gt ? ohi : fhi;
            flo = gt ? olo : flo;
        }
        // unpack winner: score + anchor index
        unsigned su = (fhi & 0x80000000u) ? (fhi ^ 0x80000000u) : ~fhi;
        const float ps = __uint_as_float(su);
        const int pi = (int)(~flo);
        const bool valid = ps > -5.0e9f;
        const int pis = (valid && (unsigned)pi < (unsigned)NANCH) ? pi : 0;
        const float4 pb = bxg[pis];          // uniform broadcast load
        if (tid == 0) {
            float* r = rois + it * 5;
            r[0] = (float)b;
            r[1] = valid ? pb.x : 0.f;
            r[2] = valid ? pb.y : 0.f;
            r[3] = valid ? pb.z : 0.f;
            r[4] = valid ? pb.w : 0.f;
            oscr[it] = valid ? ps : 0.f;
        }
        const float parea = (pb.z - pb.x + 1.f) * (pb.w - pb.y + 1.f);
#pragma unroll
        for (int k = 0; k < 24; k++) {
            float xx1 = fmaxf(pb.x, bx1[k]);
            float yy1 = fmaxf(pb.y, by1[k]);
            float xx2 = fminf(pb.z, bx2[k]);
            float yy2 = fminf(pb.w, by2[k]);
            float iw = fmaxf(xx2 - xx1 + 1.f, 0.f);
            float ih = fmaxf(yy2 - yy1 + 1.f, 0.f);
            float inter = iw * ih;
            float iou = inter / (parea + ar[k] - inter);
            if (iou > 0.7f) khi[k] = DEADHI;
        }
    }
}

// =====================================================================
extern "C" void kernel_launch(void* const* d_in, const int* in_sizes, int n_in,
                              void* d_out, int out_size, void* d_ws, size_t ws_size,
                              hipStream_t stream)
{
    const float* base_feat = (const float*)d_in[0];
    const float* im_info   = (const float*)d_in[1];
    const float* conv_w    = (const float*)d_in[4];
    const float* conv_b    = (const float*)d_in[5];
    const float* cls_w     = (const float*)d_in[6];
    const float* cls_b     = (const float*)d_in[7];
    const float* bbox_w    = (const float*)d_in[8];
    const float* bbox_b    = (const float*)d_in[9];

    float* ws  = (float*)d_ws;
    float* X   = ws + X_OFF;
    float* SC  = ws + SC_OFF;
    float* BX  = ws + BX_OFF;
    float* CSC = ws + CSC_OFF;
    float* CBX = ws + CBX_OFF;
    int*   CIX = (int*)(ws + CIX_OFF);
    u16*   WTH = (u16*)(ws + WTH_OFF);
    u16*   WTL = (u16*)(ws + WTL_OFF);
    u16*   XHp = (u16*)(ws + XH_OFF);
    u16*   XLp = (u16*)(ws + XL_OFF);
    float* ZPf = ws + ZP_OFF;
    const u16* ZPu = (const u16*)ZPf;
    float* out = (float*)d_out;

    hipLaunchKernelGGL(prep_wtk, dim3(18432), dim3(256), 0, stream,
                       conv_w, WTH, WTL, ZPf);
    hipLaunchKernelGGL(prep_act, dim3(4096), dim3(256), 0, stream,
                       base_feat, XHp, XLp);
    hipLaunchKernelGGL(conv3_mfma, dim3(128, 4), dim3(256), 0, stream,
                       WTH, WTL, XHp, XLp, ZPu, conv_b, X);
    hipLaunchKernelGGL(heads_kernel, dim3(64), dim3(256), 0, stream,
                       X, cls_w, cls_b, bbox_w, bbox_b, im_info, SC, BX);
    hipLaunchKernelGGL(select_kernel, dim3(4), dim3(1024), 0, stream,
                       SC, BX, CSC, CBX, CIX);
    hipLaunchKernelGGL(nms_kernel, dim3(4), dim3(256), 0, stream,
                       CSC, CBX, CIX, BX, out);
}

// Round 7
// 1385.042 us; speedup vs baseline: 2.6438x; 1.2790x over previous
//
#include <hip/hip_runtime.h>
#include <stdint.h>

#define HH_ 64
#define WW_ 64
#define NB 4
#define CIN 1024
#define CMID 512
#define NANCH (HH_*WW_*9)      // 36864
#define PRE_N 6000
#define POST_N 300
#define CAND_PAD 6144
#define NEGV (-1.0e10f)
#define LO_SCL 2048.0f         // 2^11
#define LO_INV 4.8828125e-4f   // 2^-11
#define MWORDS 192             // CAND_PAD/32 suppression-mask words per row

typedef unsigned short u16;
typedef unsigned long long u64;
typedef __attribute__((ext_vector_type(8))) _Float16 f16x8;
typedef __attribute__((ext_vector_type(4))) float f32x4;

#define AS1 __attribute__((address_space(1)))
#define AS3 __attribute__((address_space(3)))

// ---------------- workspace layout (float units) ----------------
// total = 30,769,408 floats = 123.1 MB (validated working)
// NMS masks (18.9 MB) alias the X region: X is dead after heads_kernel.
#define X_OFF   0
#define X_SZ    (NB*CMID*HH_*WW_)        // 8,388,608
#define SC_OFF  (X_OFF + X_SZ)
#define SC_SZ   (NB*NANCH)               // 147,456
#define BX_OFF  (SC_OFF + SC_SZ)
#define BX_SZ   (NB*NANCH*4)             // 589,824
#define CSC_OFF (BX_OFF + BX_SZ)
#define CSC_SZ  (NB*CAND_PAD)
#define CBX_OFF (CSC_OFF + CSC_SZ)
#define CBX_SZ  (NB*CAND_PAD*4)
#define CIX_OFF (CBX_OFF + CBX_SZ)
#define CIX_SZ  (NB*CAND_PAD)
#define WTH_OFF (CIX_OFF + CIX_SZ)
#define WTH_SZ  (9*512*1024/2)           // fp16 hi weights [r][co][ci_perm]
#define WTL_OFF (WTH_OFF + WTH_SZ)
#define WTL_SZ  WTH_SZ
#define XH_OFF  (WTL_OFF + WTL_SZ)
#define XH_SZ   (NB*4096*1024/2)         // fp16 hi acts NHWC [b][sp][ci_perm]
#define XL_OFF  (XH_OFF + XH_SZ)
#define XL_SZ   XH_SZ
#define ZP_OFF  (XL_OFF + XL_SZ)
#define ZP_SZ   256

// ---------------- helpers ----------------
__device__ __forceinline__ void gl2lds16(const void* g, void* l) {
    __builtin_amdgcn_global_load_lds((const AS1 unsigned int*)g,
                                     (AS3 unsigned int*)l, 16, 0, 0);
}
union fh_u { _Float16 h; u16 u; };
__device__ __forceinline__ u16 f2h_hi(float x) {
    fh_u c; c.h = (_Float16)x; return c.u;
}
__device__ __forceinline__ u16 f2h_lo(float x, u16 hi) {
    fh_u c; c.u = hi;
    float hf = (float)c.h;
    fh_u d; d.h = (_Float16)((x - hf) * LO_SCL);
    return d.u;
}
// slot->channel map within each 32-chunk (matches MFMA per-lane k grouping).
__device__ __forceinline__ int cperm(int c) {
    int blk = c >> 5, w = c & 31;
    int pos = (w < 16) ? (((w >> 2) << 3) + (w & 3))
                       : ((((w - 16) >> 2) << 3) + 4 + (w & 3));
    return (blk << 5) + pos;
}
// order-preserving float->u32 (monotonic for all finite floats)
__device__ __forceinline__ unsigned fflip(unsigned u) {
    return (u & 0x80000000u) ? ~u : (u | 0x80000000u);
}

// =====================================================================
// Prep A: conv weights fp32 [co][ci][3][3] -> fp16 hi / scaled-lo
// [r][co][ci_perm]. w = hi + lo*2^-11. Also zeroes the halo zero-page.
// =====================================================================
__global__ __launch_bounds__(256) void prep_wtk(
    const float* __restrict__ conv_w, u16* __restrict__ WTH,
    u16* __restrict__ WTL, float* __restrict__ ZP)
{
    int o = blockIdx.x * 256 + threadIdx.x;      // < 4,718,592
    int ci = o & 1023, co = (o >> 10) & 511, r = o >> 19;
    float v = conv_w[((size_t)(co * 1024 + ci)) * 9 + r];
    u16 h  = f2h_hi(v);
    u16 lo = f2h_lo(v, h);
    size_t d = (((size_t)(r * 512 + co)) << 10) + cperm(ci);
    WTH[d] = h; WTL[d] = lo;
    if (o < 256) ZP[o] = 0.f;
}

// =====================================================================
// Prep B: activations fp32 NCHW -> fp16 hi/scaled-lo NHWC [b][sp][ci_perm]
// =====================================================================
__global__ __launch_bounds__(256) void prep_act(
    const float* __restrict__ in, u16* __restrict__ XH, u16* __restrict__ XL)
{
    __shared__ float T[64][65];
    const int blk = blockIdx.x;                  // 4 * 16 * 64 = 4096
    const int b   = blk >> 10;
    const int ci0 = ((blk >> 6) & 15) << 6;
    const int sp0 = (blk & 63) << 6;
    const int tid = threadIdx.x;
    const int tq  = tid >> 6;                    // 0..3
    const int t64 = tid & 63;
#pragma unroll
    for (int w = 0; w < 16; w++) {
        int ci_l = w * 4 + tq;
        T[ci_l][t64] = in[(((size_t)(b * 1024 + ci0 + ci_l)) << 12) + sp0 + t64];
    }
    __syncthreads();
#pragma unroll
    for (int w = 0; w < 16; w++) {
        int sp_l = w * 4 + tq;
        float x = T[t64][sp_l];
        u16 h  = f2h_hi(x);
        u16 lo = f2h_lo(x, h);
        size_t d = (((size_t)((b << 12) + sp0 + sp_l)) << 10) + ci0 + cperm(t64);
        XH[d] = h; XL[d] = lo;
    }
}

// =====================================================================
// Kernel 1: 3x3 conv as scaled-split-fp16 MFMA implicit GEMM (proven).
// =====================================================================
__global__ __launch_bounds__(256, 2) void conv3_mfma(
    const u16* __restrict__ WTH, const u16* __restrict__ WTL,
    const u16* __restrict__ XH, const u16* __restrict__ XL,
    const u16* __restrict__ ZP, const float* __restrict__ bias,
    float* __restrict__ Xout)
{
    __shared__ u16 Ah_s[2][4096];
    __shared__ u16 Al_s[2][4096];
    __shared__ u16 Bh_s[2][4096];
    __shared__ u16 Bl_s[2][4096];

    const int tid = threadIdx.x;
    const int bn  = blockIdx.x;              // 0..127
    const int bm  = blockIdx.y;              // 0..3
    const int l   = tid & 63;
    const int wid = tid >> 6, wm = wid >> 1, wn = wid & 1;

    const int rowq = tid >> 2;
    const int c8   = (tid & 3) << 3;

    int spb[2]; unsigned vmq[2];
#pragma unroll
    for (int q = 0; q < 2; q++) {
        int n = bn * 128 + q * 64 + rowq;
        int yy = (n >> 6) & 63, xx = n & 63;
        spb[q] = n;
        unsigned m9 = 0;
#pragma unroll
        for (int rr = 0; rr < 9; rr++) {
            int dy = rr / 3 - 1, dx = rr % 3 - 1;
            if ((unsigned)(yy + dy) < 64u && (unsigned)(xx + dx) < 64u)
                m9 |= 1u << rr;
        }
        vmq[q] = m9;
    }

    f32x4 acc0[4][4], acc1[4][4];
#pragma unroll
    for (int i = 0; i < 4; i++)
#pragma unroll
        for (int j = 0; j < 4; j++) { acc0[i][j] = (f32x4)0.f; acc1[i][j] = (f32x4)0.f; }

    const int NK = 288;                      // 9216/32

    auto stage = [&](int sb, int kt) {
        const int r   = kt >> 5;
        const int ci0 = (kt & 31) << 5;
        const int kr  = (r * 11) >> 5;       // r/3 for r<9
        const int sh  = (kr - 1) * 64 + (r - 3 * kr - 1);
        const size_t wbase = (((size_t)(r * 512 + bm * 128)) << 10) + ci0 + c8;
        u16* ah = &Ah_s[sb][tid * 8];
        u16* al = &Al_s[sb][tid * 8];
        u16* bh = &Bh_s[sb][tid * 8];
        u16* bl = &Bl_s[sb][tid * 8];
#pragma unroll
        for (int q = 0; q < 2; q++) {
            const size_t aoff = wbase + (((size_t)(q * 64 + rowq)) << 10);
            gl2lds16(WTH + aoff, ah + q * 2048);
            gl2lds16(WTL + aoff, al + q * 2048);
            const bool v = (vmq[q] >> r) & 1u;
            const size_t boff = (((size_t)(spb[q] + sh)) << 10) + ci0 + c8;
            gl2lds16(v ? (XH + boff) : ZP, bh + q * 2048);
            gl2lds16(v ? (XL + boff) : ZP, bl + q * 2048);
        }
    };

    stage(0, 0);
    int buf = 0;
    for (int kt = 0; kt < NK; ++kt) {
        __syncthreads();
        if (kt + 1 < NK) stage(buf ^ 1, kt + 1);
        {
            const int lo16 = l & 15, hi4 = l >> 4;
            const int aoff = (wm * 64 + lo16) * 32 + hi4 * 8;
            const int boff = (wn * 64 + lo16) * 32 + hi4 * 8;
            f16x8 ah[4], av[4], bh[4], bv[4];
#pragma unroll
            for (int i = 0; i < 4; i++) {
                ah[i] = *(const f16x8*)&Ah_s[buf][aoff + i * 512];
                av[i] = *(const f16x8*)&Al_s[buf][aoff + i * 512];
                bh[i] = *(const f16x8*)&Bh_s[buf][boff + i * 512];
                bv[i] = *(const f16x8*)&Bl_s[buf][boff + i * 512];
            }
#pragma unroll
            for (int mi = 0; mi < 4; mi++)
#pragma unroll
                for (int ni = 0; ni < 4; ni++) {
                    acc0[mi][ni] = __builtin_amdgcn_mfma_f32_16x16x32_f16(
                        ah[mi], bh[ni], acc0[mi][ni], 0, 0, 0);
                    acc1[mi][ni] = __builtin_amdgcn_mfma_f32_16x16x32_f16(
                        ah[mi], bv[ni], acc1[mi][ni], 0, 0, 0);
                    acc1[mi][ni] = __builtin_amdgcn_mfma_f32_16x16x32_f16(
                        av[mi], bh[ni], acc1[mi][ni], 0, 0, 0);
                }
        }
        buf ^= 1;
    }

    // epilogue: combine + bias + relu -> X NCHW fp32.
#pragma unroll
    for (int mi = 0; mi < 4; mi++) {
        const int co0 = bm * 128 + wm * 64 + mi * 16 + ((l >> 4) << 2);
        const f32x4 b4 = *(const f32x4*)&bias[co0];
#pragma unroll
        for (int ni = 0; ni < 4; ni++) {
            const int n = bn * 128 + wn * 64 + ni * 16 + (l & 15);
            const int b = n >> 12, sp = n & 4095;
            f32x4 v0 = acc0[mi][ni], v1 = acc1[mi][ni];
            float* xo = Xout + (((size_t)(b * 512 + co0)) << 12) + sp;
            xo[0]        = fmaxf(fmaf(v1[0], LO_INV, v0[0]) + b4[0], 0.f);
            xo[4096]     = fmaxf(fmaf(v1[1], LO_INV, v0[1]) + b4[1], 0.f);
            xo[2 * 4096] = fmaxf(fmaf(v1[2], LO_INV, v0[2]) + b4[2], 0.f);
            xo[3 * 4096] = fmaxf(fmaf(v1[3], LO_INV, v0[3]) + b4[3], 0.f);
        }
    }
}

// =====================================================================
// Kernel 2: 1x1 heads + softmax + box decode + clip (unchanged).
// =====================================================================
__global__ __launch_bounds__(256) void heads_kernel(
    const float* __restrict__ X, const float* __restrict__ cls_w,
    const float* __restrict__ cls_b, const float* __restrict__ bbox_w,
    const float* __restrict__ bbox_b, const float* __restrict__ im_info,
    float* __restrict__ SC, float* __restrict__ BXo)
{
    __shared__ float Ws[54][64];
    const int tid = threadIdx.x;
    const int blk = blockIdx.x;            // 0..63
    const int b   = blk >> 4;
    const int s   = ((blk & 15) << 8) + tid;

    float acc[54];
#pragma unroll
    for (int j = 0; j < 18; j++) acc[j] = cls_b[j];
#pragma unroll
    for (int j = 0; j < 36; j++) acc[18 + j] = bbox_b[j];

    const float* xp = X + (size_t)b * CMID * 4096 + s;
    for (int c0 = 0; c0 < 512; c0 += 64) {
        __syncthreads();
        for (int e = tid; e < 54 * 64; e += 256) {
            int j = e >> 6, ci = e & 63;
            Ws[j][ci] = (j < 18) ? cls_w[j * 512 + c0 + ci]
                                 : bbox_w[(j - 18) * 512 + c0 + ci];
        }
        __syncthreads();
        for (int ci = 0; ci < 64; ci += 4) {
            float x0 = xp[(size_t)(c0 + ci) * 4096];
            float x1 = xp[(size_t)(c0 + ci + 1) * 4096];
            float x2 = xp[(size_t)(c0 + ci + 2) * 4096];
            float x3 = xp[(size_t)(c0 + ci + 3) * 4096];
#pragma unroll
            for (int j = 0; j < 54; j++) {
                float4 w4 = *(const float4*)&Ws[j][ci];
                acc[j] = fmaf(x3, w4.w, fmaf(x2, w4.z, fmaf(x1, w4.y, fmaf(x0, w4.x, acc[j]))));
            }
        }
    }

    const float imh = im_info[b * 3 + 0];
    const float imw = im_info[b * 3 + 1];
    const int hh = s >> 6, ww = s & 63;
    const float cxa = 7.5f + 16.f * (float)ww;
    const float cya = 7.5f + 16.f * (float)hh;
    const float WA[9] = {184.f, 368.f, 736.f, 128.f, 256.f, 512.f, 88.f, 176.f, 352.f};
    const float HA[9] = {96.f, 192.f, 384.f, 128.f, 256.f, 512.f, 176.f, 352.f, 704.f};
    const size_t base = (size_t)b * NANCH + (size_t)s * 9;
#pragma unroll
    for (int c = 0; c < 9; c++) {
        float bg = acc[c], fg = acc[9 + c];
        float m  = fmaxf(bg, fg);
        float e0 = expf(bg - m), e1 = expf(fg - m);
        float p  = e1 / (e0 + e1);
        float dx = acc[18 + 4 * c], dy = acc[19 + 4 * c];
        float dw = acc[20 + 4 * c], dh = acc[21 + 4 * c];
        float wa = WA[c], ha = HA[c];
        float cx = dx * wa + cxa;
        float cy = dy * ha + cya;
        float pw = expf(dw) * wa;
        float ph = expf(dh) * ha;
        float x1 = cx - 0.5f * pw, y1 = cy - 0.5f * ph;
        float x2 = cx + 0.5f * pw, y2 = cy + 0.5f * ph;
        x1 = fminf(fmaxf(x1, 0.f), imw - 1.f);
        y1 = fminf(fmaxf(y1, 0.f), imh - 1.f);
        x2 = fminf(fmaxf(x2, 0.f), imw - 1.f);
        y2 = fminf(fmaxf(y2, 0.f), imh - 1.f);
        SC[base + c] = p;
        *(float4*)&BXo[(base + c) * 4] = make_float4(x1, y1, x2, y2);
    }
}

// =====================================================================
// Kernel 3: per-batch exact top-6000 selection.
// (CBX writes removed -- sort_kernel regenerates CBX in sorted order.)
// =====================================================================
__global__ __launch_bounds__(1024) void select_kernel(
    const float* __restrict__ SC,
    float* __restrict__ CSC, int* __restrict__ CIX)
{
    const int b = blockIdx.x, tid = threadIdx.x;
    const float* sc = SC + (size_t)b * NANCH;
    const unsigned* bits = (const unsigned*)sc;
    __shared__ int s_cnt;
    __shared__ int s_c1, s_c2;
    __shared__ int s_tie[8192];

    unsigned lo = 0u, hi = 0x3f800001u;
    while (hi - lo > 1u) {
        unsigned mid = lo + ((hi - lo) >> 1);
        if (tid == 0) s_cnt = 0;
        __syncthreads();
        int c = 0;
        for (int i = tid; i < NANCH; i += 1024) c += (bits[i] >= mid) ? 1 : 0;
#pragma unroll
        for (int off = 32; off; off >>= 1) c += __shfl_down(c, off);
        if ((tid & 63) == 0) atomicAdd(&s_cnt, c);
        __syncthreads();
        int total = s_cnt;
        __syncthreads();
        if (total >= PRE_N) lo = mid; else hi = mid;
    }
    const unsigned ustar = lo;

    if (tid == 0) s_cnt = 0;
    __syncthreads();
    {
        int c = 0;
        for (int i = tid; i < NANCH; i += 1024) c += (bits[i] > ustar) ? 1 : 0;
#pragma unroll
        for (int off = 32; off; off >>= 1) c += __shfl_down(c, off);
        if ((tid & 63) == 0) atomicAdd(&s_cnt, c);
    }
    __syncthreads();
    const int n1 = s_cnt;
    __syncthreads();

    if (tid == 0) { s_c1 = 0; s_c2 = 0; }
    __syncthreads();

    float*  csc  = CSC + (size_t)b * CAND_PAD;
    int*    cix  = CIX + (size_t)b * CAND_PAD;

    for (int i = tid; i < NANCH; i += 1024) {
        unsigned u = bits[i];
        if (u > ustar) {
            int p = atomicAdd(&s_c1, 1);
            csc[p] = sc[i]; cix[p] = i;
        } else if (u == ustar) {
            int p = atomicAdd(&s_c2, 1);
            if (p < 8192) s_tie[p] = i;
        }
    }
    __syncthreads();
    int m = s_c2; if (m > 8192) m = 8192;
    const int need = PRE_N - n1;
    for (int i = tid; i < 8192; i += 1024)
        if (i >= m) s_tie[i] = 0x7fffffff;
    __syncthreads();

    for (int k = 2; k <= 8192; k <<= 1) {
        for (int j = k >> 1; j > 0; j >>= 1) {
            for (int t = tid; t < 8192; t += 1024) {
                int ixj = t ^ j;
                if (ixj > t) {
                    int va = s_tie[t], vb = s_tie[ixj];
                    bool up = ((t & k) == 0);
                    if ((va > vb) == up) { s_tie[t] = vb; s_tie[ixj] = va; }
                }
            }
            __syncthreads();
        }
    }
    for (int t = tid; t < need; t += 1024) {
        int i = s_tie[t];
        int p = n1 + t;
        if (i >= 0 && i < NANCH) {
            csc[p] = sc[i]; cix[p] = i;
        } else {
            csc[p] = -2.0e10f; cix[p] = 0x7fffffff;
        }
    }
    for (int p = PRE_N + tid; p < CAND_PAD; p += 1024) {
        csc[p] = -2.0e10f;
        cix[p] = 0x7fffffff;
    }
}

// =====================================================================
// Kernel 4a: sort candidates by (score desc, anchor idx asc).
// Packed u64 keys (flip(score)<<32 | ~cix) -- key ordering HW-validated
// in R6. Bitonic over 8192 in LDS; rewrites CSC/CIX sorted and gathers
// sorted boxes from BX into CBX.
// =====================================================================
__global__ __launch_bounds__(1024) void sort_kernel(
    float* __restrict__ CSC, float* __restrict__ CBX,
    int* __restrict__ CIX, const float* __restrict__ BX)
{
    const int b = blockIdx.x, tid = threadIdx.x;
    float* csc = CSC + (size_t)b * CAND_PAD;
    int*   cix = CIX + (size_t)b * CAND_PAD;
    float4* cbx4 = (float4*)CBX + (size_t)b * CAND_PAD;
    const float4* bx4 = (const float4*)BX + (size_t)b * NANCH;
    __shared__ u64 sk[8192];

    for (int i = tid; i < 8192; i += 1024) {
        u64 key = 0ull;                       // filler sorts last
        if (i < CAND_PAD) {
            unsigned khi = fflip(__float_as_uint(csc[i]));
            unsigned klo = ~((unsigned)cix[i]);
            key = ((u64)khi << 32) | klo;
        }
        sk[i] = key;
    }
    __syncthreads();
    for (int k = 2; k <= 8192; k <<= 1) {
        for (int j = k >> 1; j > 0; j >>= 1) {
            for (int t = tid; t < 8192; t += 1024) {
                int ixj = t ^ j;
                if (ixj > t) {
                    u64 a = sk[t], c2 = sk[ixj];
                    bool up = ((t & k) == 0);
                    if ((a < c2) == up) { sk[t] = c2; sk[ixj] = a; }  // descending
                }
            }
            __syncthreads();
        }
    }
    for (int i = tid; i < CAND_PAD; i += 1024) {
        u64 key = sk[i];
        unsigned khi = (unsigned)(key >> 32), klo = (unsigned)key;
        unsigned su = (khi & 0x80000000u) ? (khi ^ 0x80000000u) : ~khi;
        float sc = __uint_as_float(su);
        int ci = (int)(~klo);
        csc[i] = sc; cix[i] = ci;
        float4 pb;
        if (sc > -5.0e9f && (unsigned)ci < (unsigned)NANCH) pb = bx4[ci];
        else pb = make_float4(-4e9f, -4e9f, -4e9f, -4e9f);
        cbx4[i] = pb;
    }
}

// =====================================================================
// Kernel 4b: pairwise suppression bitmasks (sorted order).
// Row i, bit j set iff IoU(box_i, box_j) > 0.7 -- expression identical
// to the proven greedy kernel. Lower-triangle tiles skipped (only bits
// j >= row-group start are ever consulted; garbage below is harmless).
// grid (96 row-groups, 4 batches) x 256 threads. MASK aliases X.
// =====================================================================
__global__ __launch_bounds__(256) void nms_mask(
    const float* __restrict__ CBX, unsigned* __restrict__ MASK)
{
    const int rg = blockIdx.x, b = blockIdx.y, tid = threadIdx.x;
    const float4* cbx = (const float4*)CBX + (size_t)b * CAND_PAD;
    unsigned* mrow = MASK + (size_t)b * CAND_PAD * MWORDS;

    __shared__ float4 rb[64];
    __shared__ float  rar[64];
    __shared__ float4 cb[1024];
    __shared__ float  car[1024];

    if (tid < 64) {
        float4 v = cbx[rg * 64 + tid];
        rb[tid] = v;
        rar[tid] = (v.z - v.x + 1.f) * (v.w - v.y + 1.f);
    }
    __syncthreads();
    const int rl = tid >> 2;                  // row 0..63 within group
    const int wq = tid & 3;
    const float4 rv = rb[rl];
    const float  ra = rar[rl];
    const size_t rbase = (size_t)(rg * 64 + rl) * MWORDS;

    for (int jt = rg >> 4; jt < 6; jt++) {    // skip strictly-lower tiles
        __syncthreads();
        for (int e = tid; e < 1024; e += 256) {
            float4 v = cbx[jt * 1024 + e];
            cb[e] = v;
            car[e] = (v.z - v.x + 1.f) * (v.w - v.y + 1.f);
        }
        __syncthreads();
#pragma unroll
        for (int k = 0; k < 8; k++) {
            const int wt = wq + 4 * k;        // word in tile 0..31
            unsigned bits = 0;
            for (int bit = 0; bit < 32; bit++) {
                const int j = wt * 32 + bit;
                float4 cv = cb[j];
                float xx1 = fmaxf(rv.x, cv.x);
                float yy1 = fmaxf(rv.y, cv.y);
                float xx2 = fminf(rv.z, cv.z);
                float yy2 = fminf(rv.w, cv.w);
                float iw = fmaxf(xx2 - xx1 + 1.f, 0.f);
                float ih = fmaxf(yy2 - yy1 + 1.f, 0.f);
                float inter = iw * ih;
                float iou = inter / (ra + car[j] - inter);
                if (iou > 0.7f) bits |= (1u << bit);
            }
            mrow[rbase + jt * 32 + wt] = bits;
        }
    }
}

// =====================================================================
// Kernel 4c: serial scan over sorted candidates using bitmasks.
// keep i iff not suppressed by any kept j<i; first 300 kept = exact
// greedy-NMS output. Chunks of 64: wave 0 resolves intra-chunk keeps
// (ballot + ctz loop, iterations = #kept); all threads OR kept rows
// into the LDS removed-mask; outputs written in kept order.
// =====================================================================
__global__ __launch_bounds__(1024) void nms_scan(
    const float* __restrict__ CSC, const float* __restrict__ CBX,
    const unsigned* __restrict__ MASK, float* __restrict__ out)
{
    const int b = blockIdx.x, tid = threadIdx.x;
    const float*  csc = CSC + (size_t)b * CAND_PAD;
    const float4* cbx = (const float4*)CBX + (size_t)b * CAND_PAD;
    const unsigned* mk = MASK + (size_t)b * CAND_PAD * MWORDS;

    __shared__ unsigned s_rm[MWORDS];
    __shared__ unsigned s_klo, s_khi;
    __shared__ int s_cnt;

    float* rois = out + (size_t)b * 1500;
    float* oscr = out + 6000 + (size_t)b * 300;

    if (tid < MWORDS) s_rm[tid] = 0u;
    if (tid == 0) s_cnt = 0;
    for (int it = tid; it < POST_N; it += 1024) {
        float* r = rois + it * 5;
        r[0] = (float)b; r[1] = 0.f; r[2] = 0.f; r[3] = 0.f; r[4] = 0.f;
        oscr[it] = 0.f;
    }
    __syncthreads();

    const int lane = tid & 63, wv = tid >> 6;
    for (int c = 0; c < 94; c++) {           // 94*64 = 6016 covers 6000 real
        int kc = s_cnt;                      // uniform (post-barrier)
        if (kc >= POST_N) break;
        if (wv == 0) {
            const int i = c * 64 + lane;
            unsigned rlo = mk[(size_t)i * MWORDS + 2 * c];
            unsigned rhi = mk[(size_t)i * MWORDS + 2 * c + 1];
            unsigned gw = s_rm[2 * c + (lane >> 5)];
            bool alive = !((gw >> (lane & 31)) & 1u) && (csc[i] > -5.0e9f);
            u64 rem = __ballot(alive);
            u64 keptm = 0ull;
            while (rem) {
                int sl = __builtin_ctzll(rem);
                keptm |= 1ull << sl;
                unsigned blo = __shfl(rlo, sl);
                unsigned bhi = __shfl(rhi, sl);
                rem &= ~(((u64)bhi << 32) | (u64)blo);
                rem &= ~(1ull << sl);
            }
            if (lane == 0) { s_klo = (unsigned)keptm; s_khi = (unsigned)(keptm >> 32); }
        }
        __syncthreads();
        u64 keptm = ((u64)s_khi << 32) | (u64)s_klo;
        int base = kc;
        while (keptm && base < POST_N) {
            int sl = __builtin_ctzll(keptm);
            keptm &= keptm - 1ull;
            const int i = c * 64 + sl;
            if (tid < MWORDS) s_rm[tid] |= mk[(size_t)i * MWORDS + tid];
            if (tid == 0) {
                float4 pb = cbx[i];
                float* r = rois + base * 5;
                r[1] = pb.x; r[2] = pb.y; r[3] = pb.z; r[4] = pb.w;
                oscr[base] = csc[i];
            }
            base++;
        }
        if (tid == 0) s_cnt = base;
        __syncthreads();
    }
}

// =====================================================================
extern "C" void kernel_launch(void* const* d_in, const int* in_sizes, int n_in,
                              void* d_out, int out_size, void* d_ws, size_t ws_size,
                              hipStream_t stream)
{
    const float* base_feat = (const float*)d_in[0];
    const float* im_info   = (const float*)d_in[1];
    const float* conv_w    = (const float*)d_in[4];
    const float* conv_b    = (const float*)d_in[5];
    const float* cls_w     = (const float*)d_in[6];
    const float* cls_b     = (const float*)d_in[7];
    const float* bbox_w    = (const float*)d_in[8];
    const float* bbox_b    = (const float*)d_in[9];

    float* ws  = (float*)d_ws;
    float* X   = ws + X_OFF;
    float* SC  = ws + SC_OFF;
    float* BX  = ws + BX_OFF;
    float* CSC = ws + CSC_OFF;
    float* CBX = ws + CBX_OFF;
    int*   CIX = (int*)(ws + CIX_OFF);
    u16*   WTH = (u16*)(ws + WTH_OFF);
    u16*   WTL = (u16*)(ws + WTL_OFF);
    u16*   XHp = (u16*)(ws + XH_OFF);
    u16*   XLp = (u16*)(ws + XL_OFF);
    float* ZPf = ws + ZP_OFF;
    const u16* ZPu = (const u16*)ZPf;
    unsigned* MASK = (unsigned*)(ws + X_OFF);   // aliases X (dead after heads)
    float* out = (float*)d_out;

    hipLaunchKernelGGL(prep_wtk, dim3(18432), dim3(256), 0, stream,
                       conv_w, WTH, WTL, ZPf);
    hipLaunchKernelGGL(prep_act, dim3(4096), dim3(256), 0, stream,
                       base_feat, XHp, XLp);
    hipLaunchKernelGGL(conv3_mfma, dim3(128, 4), dim3(256), 0, stream,
                       WTH, WTL, XHp, XLp, ZPu, conv_b, X);
    hipLaunchKernelGGL(heads_kernel, dim3(64), dim3(256), 0, stream,
                       X, cls_w, cls_b, bbox_w, bbox_b, im_info, SC, BX);
    hipLaunchKernelGGL(select_kernel, dim3(4), dim3(1024), 0, stream,
                       SC, CSC, CIX);
    hipLaunchKernelGGL(sort_kernel, dim3(4), dim3(1024), 0, stream,
                       CSC, CBX, CIX, BX);
    hipLaunchKernelGGL(nms_mask, dim3(96, 4), dim3(256), 0, stream,
                       CBX, MASK);
    hipLaunchKernelGGL(nms_scan, dim3(4), dim3(1024), 0, stream,
                       CSC, CBX, MASK, out);
}

// Round 8
// 1253.651 us; speedup vs baseline: 2.9209x; 1.1048x over previous
//
#include <hip/hip_runtime.h>
#include <stdint.h>

#define HH_ 64
#define WW_ 64
#define NB 4
#define CIN 1024
#define CMID 512
#define NANCH (HH_*WW_*9)      // 36864
#define PRE_N 6000
#define POST_N 300
#define CAND_PAD 6144
#define NEGV (-1.0e10f)
#define LO_SCL 2048.0f         // 2^11
#define LO_INV 4.8828125e-4f   // 2^-11
#define MWORDS 192             // CAND_PAD/32 suppression-mask words per row

typedef unsigned short u16;
typedef unsigned long long u64;
typedef __attribute__((ext_vector_type(8))) _Float16 f16x8;
typedef __attribute__((ext_vector_type(4))) float f32x4;

#define AS1 __attribute__((address_space(1)))
#define AS3 __attribute__((address_space(3)))

// ---------------- workspace layout (float units) ----------------
// total = 30,769,408 floats = 123.1 MB (validated working)
// NMS masks (18.9 MB) alias the X region: X is dead after heads_kernel.
#define X_OFF   0
#define X_SZ    (NB*CMID*HH_*WW_)        // 8,388,608
#define SC_OFF  (X_OFF + X_SZ)
#define SC_SZ   (NB*NANCH)               // 147,456
#define BX_OFF  (SC_OFF + SC_SZ)
#define BX_SZ   (NB*NANCH*4)             // 589,824
#define CSC_OFF (BX_OFF + BX_SZ)
#define CSC_SZ  (NB*CAND_PAD)
#define CBX_OFF (CSC_OFF + CSC_SZ)
#define CBX_SZ  (NB*CAND_PAD*4)
#define CIX_OFF (CBX_OFF + CBX_SZ)
#define CIX_SZ  (NB*CAND_PAD)
#define WTH_OFF (CIX_OFF + CIX_SZ)
#define WTH_SZ  (9*512*1024/2)           // fp16 hi weights [r][co][ci_perm]
#define WTL_OFF (WTH_OFF + WTH_SZ)
#define WTL_SZ  WTH_SZ
#define XH_OFF  (WTL_OFF + WTL_SZ)
#define XH_SZ   (NB*4096*1024/2)         // fp16 hi acts NHWC [b][sp][ci_perm]
#define XL_OFF  (XH_OFF + XH_SZ)
#define XL_SZ   XH_SZ
#define ZP_OFF  (XL_OFF + XL_SZ)
#define ZP_SZ   256

// ---------------- helpers ----------------
__device__ __forceinline__ void gl2lds16(const void* g, void* l) {
    __builtin_amdgcn_global_load_lds((const AS1 unsigned int*)g,
                                     (AS3 unsigned int*)l, 16, 0, 0);
}
union fh_u { _Float16 h; u16 u; };
__device__ __forceinline__ u16 f2h_hi(float x) {
    fh_u c; c.h = (_Float16)x; return c.u;
}
__device__ __forceinline__ u16 f2h_lo(float x, u16 hi) {
    fh_u c; c.u = hi;
    float hf = (float)c.h;
    fh_u d; d.h = (_Float16)((x - hf) * LO_SCL);
    return d.u;
}
// slot->channel map within each 32-chunk (matches MFMA per-lane k grouping).
__device__ __forceinline__ int cperm(int c) {
    int blk = c >> 5, w = c & 31;
    int pos = (w < 16) ? (((w >> 2) << 3) + (w & 3))
                       : ((((w - 16) >> 2) << 3) + 4 + (w & 3));
    return (blk << 5) + pos;
}
// order-preserving float->u32 (monotonic for all finite floats)
__device__ __forceinline__ unsigned fflip(unsigned u) {
    return (u & 0x80000000u) ? ~u : (u | 0x80000000u);
}

// =====================================================================
// Prep A: conv weights fp32 [co][ci][3][3] -> fp16 hi / scaled-lo
// [r][co][ci_perm]. w = hi + lo*2^-11. Also zeroes the halo zero-page.
// =====================================================================
__global__ __launch_bounds__(256) void prep_wtk(
    const float* __restrict__ conv_w, u16* __restrict__ WTH,
    u16* __restrict__ WTL, float* __restrict__ ZP)
{
    int o = blockIdx.x * 256 + threadIdx.x;      // < 4,718,592
    int ci = o & 1023, co = (o >> 10) & 511, r = o >> 19;
    float v = conv_w[((size_t)(co * 1024 + ci)) * 9 + r];
    u16 h  = f2h_hi(v);
    u16 lo = f2h_lo(v, h);
    size_t d = (((size_t)(r * 512 + co)) << 10) + cperm(ci);
    WTH[d] = h; WTL[d] = lo;
    if (o < 256) ZP[o] = 0.f;
}

// =====================================================================
// Prep B: activations fp32 NCHW -> fp16 hi/scaled-lo NHWC [b][sp][ci_perm]
// =====================================================================
__global__ __launch_bounds__(256) void prep_act(
    const float* __restrict__ in, u16* __restrict__ XH, u16* __restrict__ XL)
{
    __shared__ float T[64][65];
    const int blk = blockIdx.x;                  // 4 * 16 * 64 = 4096
    const int b   = blk >> 10;
    const int ci0 = ((blk >> 6) & 15) << 6;
    const int sp0 = (blk & 63) << 6;
    const int tid = threadIdx.x;
    const int tq  = tid >> 6;                    // 0..3
    const int t64 = tid & 63;
#pragma unroll
    for (int w = 0; w < 16; w++) {
        int ci_l = w * 4 + tq;
        T[ci_l][t64] = in[(((size_t)(b * 1024 + ci0 + ci_l)) << 12) + sp0 + t64];
    }
    __syncthreads();
#pragma unroll
    for (int w = 0; w < 16; w++) {
        int sp_l = w * 4 + tq;
        float x = T[t64][sp_l];
        u16 h  = f2h_hi(x);
        u16 lo = f2h_lo(x, h);
        size_t d = (((size_t)((b << 12) + sp0 + sp_l)) << 10) + ci0 + cperm(t64);
        XH[d] = h; XL[d] = lo;
    }
}

// =====================================================================
// Kernel 1: 3x3 conv as scaled-split-fp16 MFMA implicit GEMM (proven).
// =====================================================================
__global__ __launch_bounds__(256, 2) void conv3_mfma(
    const u16* __restrict__ WTH, const u16* __restrict__ WTL,
    const u16* __restrict__ XH, const u16* __restrict__ XL,
    const u16* __restrict__ ZP, const float* __restrict__ bias,
    float* __restrict__ Xout)
{
    __shared__ u16 Ah_s[2][4096];
    __shared__ u16 Al_s[2][4096];
    __shared__ u16 Bh_s[2][4096];
    __shared__ u16 Bl_s[2][4096];

    const int tid = threadIdx.x;
    const int bn  = blockIdx.x;              // 0..127
    const int bm  = blockIdx.y;              // 0..3
    const int l   = tid & 63;
    const int wid = tid >> 6, wm = wid >> 1, wn = wid & 1;

    const int rowq = tid >> 2;
    const int c8   = (tid & 3) << 3;

    int spb[2]; unsigned vmq[2];
#pragma unroll
    for (int q = 0; q < 2; q++) {
        int n = bn * 128 + q * 64 + rowq;
        int yy = (n >> 6) & 63, xx = n & 63;
        spb[q] = n;
        unsigned m9 = 0;
#pragma unroll
        for (int rr = 0; rr < 9; rr++) {
            int dy = rr / 3 - 1, dx = rr % 3 - 1;
            if ((unsigned)(yy + dy) < 64u && (unsigned)(xx + dx) < 64u)
                m9 |= 1u << rr;
        }
        vmq[q] = m9;
    }

    f32x4 acc0[4][4], acc1[4][4];
#pragma unroll
    for (int i = 0; i < 4; i++)
#pragma unroll
        for (int j = 0; j < 4; j++) { acc0[i][j] = (f32x4)0.f; acc1[i][j] = (f32x4)0.f; }

    const int NK = 288;                      // 9216/32

    auto stage = [&](int sb, int kt) {
        const int r   = kt >> 5;
        const int ci0 = (kt & 31) << 5;
        const int kr  = (r * 11) >> 5;       // r/3 for r<9
        const int sh  = (kr - 1) * 64 + (r - 3 * kr - 1);
        const size_t wbase = (((size_t)(r * 512 + bm * 128)) << 10) + ci0 + c8;
        u16* ah = &Ah_s[sb][tid * 8];
        u16* al = &Al_s[sb][tid * 8];
        u16* bh = &Bh_s[sb][tid * 8];
        u16* bl = &Bl_s[sb][tid * 8];
#pragma unroll
        for (int q = 0; q < 2; q++) {
            const size_t aoff = wbase + (((size_t)(q * 64 + rowq)) << 10);
            gl2lds16(WTH + aoff, ah + q * 2048);
            gl2lds16(WTL + aoff, al + q * 2048);
            const bool v = (vmq[q] >> r) & 1u;
            const size_t boff = (((size_t)(spb[q] + sh)) << 10) + ci0 + c8;
            gl2lds16(v ? (XH + boff) : ZP, bh + q * 2048);
            gl2lds16(v ? (XL + boff) : ZP, bl + q * 2048);
        }
    };

    stage(0, 0);
    int buf = 0;
    for (int kt = 0; kt < NK; ++kt) {
        __syncthreads();
        if (kt + 1 < NK) stage(buf ^ 1, kt + 1);
        {
            const int lo16 = l & 15, hi4 = l >> 4;
            const int aoff = (wm * 64 + lo16) * 32 + hi4 * 8;
            const int boff = (wn * 64 + lo16) * 32 + hi4 * 8;
            f16x8 ah[4], av[4], bh[4], bv[4];
#pragma unroll
            for (int i = 0; i < 4; i++) {
                ah[i] = *(const f16x8*)&Ah_s[buf][aoff + i * 512];
                av[i] = *(const f16x8*)&Al_s[buf][aoff + i * 512];
                bh[i] = *(const f16x8*)&Bh_s[buf][boff + i * 512];
                bv[i] = *(const f16x8*)&Bl_s[buf][boff + i * 512];
            }
#pragma unroll
            for (int mi = 0; mi < 4; mi++)
#pragma unroll
                for (int ni = 0; ni < 4; ni++) {
                    acc0[mi][ni] = __builtin_amdgcn_mfma_f32_16x16x32_f16(
                        ah[mi], bh[ni], acc0[mi][ni], 0, 0, 0);
                    acc1[mi][ni] = __builtin_amdgcn_mfma_f32_16x16x32_f16(
                        ah[mi], bv[ni], acc1[mi][ni], 0, 0, 0);
                    acc1[mi][ni] = __builtin_amdgcn_mfma_f32_16x16x32_f16(
                        av[mi], bh[ni], acc1[mi][ni], 0, 0, 0);
                }
        }
        buf ^= 1;
    }

    // epilogue: combine + bias + relu -> X NCHW fp32.
#pragma unroll
    for (int mi = 0; mi < 4; mi++) {
        const int co0 = bm * 128 + wm * 64 + mi * 16 + ((l >> 4) << 2);
        const f32x4 b4 = *(const f32x4*)&bias[co0];
#pragma unroll
        for (int ni = 0; ni < 4; ni++) {
            const int n = bn * 128 + wn * 64 + ni * 16 + (l & 15);
            const int b = n >> 12, sp = n & 4095;
            f32x4 v0 = acc0[mi][ni], v1 = acc1[mi][ni];
            float* xo = Xout + (((size_t)(b * 512 + co0)) << 12) + sp;
            xo[0]        = fmaxf(fmaf(v1[0], LO_INV, v0[0]) + b4[0], 0.f);
            xo[4096]     = fmaxf(fmaf(v1[1], LO_INV, v0[1]) + b4[1], 0.f);
            xo[2 * 4096] = fmaxf(fmaf(v1[2], LO_INV, v0[2]) + b4[2], 0.f);
            xo[3 * 4096] = fmaxf(fmaf(v1[3], LO_INV, v0[3]) + b4[3], 0.f);
        }
    }
}

// =====================================================================
// Kernel 2: 1x1 heads v2 -- W staged in 2x(54x256) LDS chunks, 4
// barriers total (was 16). Per-thread summation order UNCHANGED
// (ci ascending, same FMA nest) -> bit-identical outputs.
// =====================================================================
__global__ __launch_bounds__(256) void heads_kernel(
    const float* __restrict__ X, const float* __restrict__ cls_w,
    const float* __restrict__ cls_b, const float* __restrict__ bbox_w,
    const float* __restrict__ bbox_b, const float* __restrict__ im_info,
    float* __restrict__ SC, float* __restrict__ BXo)
{
    __shared__ __attribute__((aligned(16))) float Ws[54][256];   // 55.3 KB
    const int tid = threadIdx.x;
    const int blk = blockIdx.x;            // 0..63
    const int b   = blk >> 4;
    const int s   = ((blk & 15) << 8) + tid;

    float acc[54];
#pragma unroll
    for (int j = 0; j < 18; j++) acc[j] = cls_b[j];
#pragma unroll
    for (int j = 0; j < 36; j++) acc[18 + j] = bbox_b[j];

    const float* xp = X + (size_t)b * CMID * 4096 + s;
    for (int c0 = 0; c0 < 512; c0 += 256) {
        __syncthreads();
        for (int e = tid; e < 54 * 256; e += 256) {
            int j = e >> 8, ci = e & 255;
            Ws[j][ci] = (j < 18) ? cls_w[j * 512 + c0 + ci]
                                 : bbox_w[(j - 18) * 512 + c0 + ci];
        }
        __syncthreads();
        for (int ci = 0; ci < 256; ci += 4) {
            float x0 = xp[(size_t)(c0 + ci) * 4096];
            float x1 = xp[(size_t)(c0 + ci + 1) * 4096];
            float x2 = xp[(size_t)(c0 + ci + 2) * 4096];
            float x3 = xp[(size_t)(c0 + ci + 3) * 4096];
#pragma unroll
            for (int j = 0; j < 54; j++) {
                float4 w4 = *(const float4*)&Ws[j][ci];
                acc[j] = fmaf(x3, w4.w, fmaf(x2, w4.z, fmaf(x1, w4.y, fmaf(x0, w4.x, acc[j]))));
            }
        }
    }

    const float imh = im_info[b * 3 + 0];
    const float imw = im_info[b * 3 + 1];
    const int hh = s >> 6, ww = s & 63;
    const float cxa = 7.5f + 16.f * (float)ww;
    const float cya = 7.5f + 16.f * (float)hh;
    const float WA[9] = {184.f, 368.f, 736.f, 128.f, 256.f, 512.f, 88.f, 176.f, 352.f};
    const float HA[9] = {96.f, 192.f, 384.f, 128.f, 256.f, 512.f, 176.f, 352.f, 704.f};
    const size_t base = (size_t)b * NANCH + (size_t)s * 9;
#pragma unroll
    for (int c = 0; c < 9; c++) {
        float bg = acc[c], fg = acc[9 + c];
        float m  = fmaxf(bg, fg);
        float e0 = expf(bg - m), e1 = expf(fg - m);
        float p  = e1 / (e0 + e1);
        float dx = acc[18 + 4 * c], dy = acc[19 + 4 * c];
        float dw = acc[20 + 4 * c], dh = acc[21 + 4 * c];
        float wa = WA[c], ha = HA[c];
        float cx = dx * wa + cxa;
        float cy = dy * ha + cya;
        float pw = expf(dw) * wa;
        float ph = expf(dh) * ha;
        float x1 = cx - 0.5f * pw, y1 = cy - 0.5f * ph;
        float x2 = cx + 0.5f * pw, y2 = cy + 0.5f * ph;
        x1 = fminf(fmaxf(x1, 0.f), imw - 1.f);
        y1 = fminf(fmaxf(y1, 0.f), imh - 1.f);
        x2 = fminf(fmaxf(x2, 0.f), imw - 1.f);
        y2 = fminf(fmaxf(y2, 0.f), imh - 1.f);
        SC[base + c] = p;
        *(float4*)&BXo[(base + c) * 4] = make_float4(x1, y1, x2, y2);
    }
}

// =====================================================================
// Kernel 3: select v2 -- exact top-6000 via 3-level histogram radix.
// ustar (6000th-largest raw score bits) found in 3 scans (13+13+6 bits)
// instead of 30 binary-search scans. n1 = count(>ustar) falls out of
// the cumulative counts. Ties placed by rank-count (exact, matches the
// old sorted-ascending-take-first-need); bitonic fallback kept for the
// pathological m>1024 case.
// =====================================================================
__global__ __launch_bounds__(1024) void select_kernel(
    const float* __restrict__ SC,
    float* __restrict__ CSC, int* __restrict__ CIX)
{
    const int b = blockIdx.x, tid = threadIdx.x;
    const int lane = tid & 63, wv = tid >> 6;
    const float* sc = SC + (size_t)b * NANCH;
    const unsigned* bits = (const unsigned*)sc;

    __shared__ unsigned s_buf[8192];     // hist, then tie list
    __shared__ unsigned s_part[1024];
    __shared__ unsigned s_wsum[16];
    __shared__ unsigned s_sel[2];
    __shared__ int s_c1, s_c2;

    // find the bin containing the target-th largest among s_buf[0..nb)
    auto findbin = [&](int nb, int bpt, unsigned target) -> uint2 {
        unsigned mysum = 0;
        const int base = tid * bpt;
        if (base < nb)
            for (int q = 0; q < bpt; q++) mysum += s_buf[base + q];
        s_part[tid] = mysum;
        unsigned wsum = mysum;
#pragma unroll
        for (int off = 32; off; off >>= 1) wsum += __shfl_down(wsum, off);
        if (lane == 0) s_wsum[wv] = wsum;
        __syncthreads();
        unsigned cum = 0;
        for (int w = wv + 1; w < 16; w++) cum += s_wsum[w];
        for (int ll = lane + 1; ll < 64; ll++) cum += s_part[(wv << 6) + ll];
        if (base < nb) {
            unsigned c = cum;
            for (int q = bpt - 1; q >= 0; q--) {
                unsigned h = s_buf[base + q];
                if (c < target && c + h >= target) { s_sel[0] = base + q; s_sel[1] = c; }
                c += h;
            }
        }
        __syncthreads();
        uint2 r; r.x = s_sel[0]; r.y = s_sel[1];
        __syncthreads();
        return r;
    };

    // ---- level 1: bits 31..19 (scores >= 0 so raw-bit order = value order)
    for (int i = tid; i < 8192; i += 1024) s_buf[i] = 0;
    __syncthreads();
    for (int i = tid; i < NANCH; i += 1024)
        atomicAdd(&s_buf[bits[i] >> 19], 1u);
    __syncthreads();
    uint2 r1 = findbin(8192, 8, PRE_N);
    const unsigned B1 = r1.x;
    unsigned target2 = PRE_N - r1.y;

    // ---- level 2: bits 18..6 within B1
    for (int i = tid; i < 8192; i += 1024) s_buf[i] = 0;
    __syncthreads();
    for (int i = tid; i < NANCH; i += 1024) {
        unsigned u = bits[i];
        if ((u >> 19) == B1) atomicAdd(&s_buf[(u >> 6) & 8191u], 1u);
    }
    __syncthreads();
    uint2 r2 = findbin(8192, 8, target2);
    const unsigned B2 = r2.x;
    unsigned target3 = target2 - r2.y;

    // ---- level 3: bits 5..0 within (B1,B2)
    for (int i = tid; i < 64; i += 1024) { }
    if (tid < 64) s_buf[tid] = 0;
    __syncthreads();
    const unsigned pref26 = (B1 << 13) | B2;
    for (int i = tid; i < NANCH; i += 1024) {
        unsigned u = bits[i];
        if ((u >> 6) == pref26) atomicAdd(&s_buf[u & 63u], 1u);
    }
    __syncthreads();
    uint2 r3 = findbin(64, 1, target3);
    const unsigned ustar = (B1 << 19) | (B2 << 6) | r3.x;
    const int n1 = (int)(r1.y + r2.y + r3.y);

    // ---- compaction (identical semantics to proven kernel) ----
    if (tid == 0) { s_c1 = 0; s_c2 = 0; }
    __syncthreads();
    float* csc = CSC + (size_t)b * CAND_PAD;
    int*   cix = CIX + (size_t)b * CAND_PAD;
    int* s_tie = (int*)s_buf;

    for (int i = tid; i < NANCH; i += 1024) {
        unsigned u = bits[i];
        if (u > ustar) {
            int p = atomicAdd(&s_c1, 1);
            csc[p] = sc[i]; cix[p] = i;
        } else if (u == ustar) {
            int p = atomicAdd(&s_c2, 1);
            if (p < 8192) s_tie[p] = i;
        }
    }
    __syncthreads();
    int m = s_c2; if (m > 8192) m = 8192;
    const int need = PRE_N - n1;

    if (m <= 1024) {
        // rank-by-count: exact placement, no sort
        if (tid < m) {
            int v = s_tie[tid];
            int r = 0;
            for (int j2 = 0; j2 < m; j2++) r += (s_tie[j2] < v) ? 1 : 0;
            if (r < need) { csc[n1 + r] = sc[v]; cix[n1 + r] = v; }
        }
    } else {
        // pathological fallback: full bitonic (as before)
        for (int i = tid; i < 8192; i += 1024)
            if (i >= m) s_tie[i] = 0x7fffffff;
        __syncthreads();
        for (int k = 2; k <= 8192; k <<= 1) {
            for (int j = k >> 1; j > 0; j >>= 1) {
                for (int t = tid; t < 8192; t += 1024) {
                    int ixj = t ^ j;
                    if (ixj > t) {
                        int va = s_tie[t], vb = s_tie[ixj];
                        bool up = ((t & k) == 0);
                        if ((va > vb) == up) { s_tie[t] = vb; s_tie[ixj] = va; }
                    }
                }
                __syncthreads();
            }
        }
        for (int t = tid; t < need; t += 1024) {
            int i = s_tie[t];
            int p = n1 + t;
            if (i >= 0 && i < NANCH) {
                csc[p] = sc[i]; cix[p] = i;
            } else {
                csc[p] = -2.0e10f; cix[p] = 0x7fffffff;
            }
        }
    }
    for (int p = PRE_N + tid; p < CAND_PAD; p += 1024) {
        csc[p] = -2.0e10f;
        cix[p] = 0x7fffffff;
    }
}

// =====================================================================
// Kernel 4a: sort candidates by (score desc, anchor idx asc) (proven).
// =====================================================================
__global__ __launch_bounds__(1024) void sort_kernel(
    float* __restrict__ CSC, float* __restrict__ CBX,
    int* __restrict__ CIX, const float* __restrict__ BX)
{
    const int b = blockIdx.x, tid = threadIdx.x;
    float* csc = CSC + (size_t)b * CAND_PAD;
    int*   cix = CIX + (size_t)b * CAND_PAD;
    float4* cbx4 = (float4*)CBX + (size_t)b * CAND_PAD;
    const float4* bx4 = (const float4*)BX + (size_t)b * NANCH;
    __shared__ u64 sk[8192];

    for (int i = tid; i < 8192; i += 1024) {
        u64 key = 0ull;                       // filler sorts last
        if (i < CAND_PAD) {
            unsigned khi = fflip(__float_as_uint(csc[i]));
            unsigned klo = ~((unsigned)cix[i]);
            key = ((u64)khi << 32) | klo;
        }
        sk[i] = key;
    }
    __syncthreads();
    for (int k = 2; k <= 8192; k <<= 1) {
        for (int j = k >> 1; j > 0; j >>= 1) {
            for (int t = tid; t < 8192; t += 1024) {
                int ixj = t ^ j;
                if (ixj > t) {
                    u64 a = sk[t], c2 = sk[ixj];
                    bool up = ((t & k) == 0);
                    if ((a < c2) == up) { sk[t] = c2; sk[ixj] = a; }  // descending
                }
            }
            __syncthreads();
        }
    }
    for (int i = tid; i < CAND_PAD; i += 1024) {
        u64 key = sk[i];
        unsigned khi = (unsigned)(key >> 32), klo = (unsigned)key;
        unsigned su = (khi & 0x80000000u) ? (khi ^ 0x80000000u) : ~khi;
        float sc = __uint_as_float(su);
        int ci = (int)(~klo);
        csc[i] = sc; cix[i] = ci;
        float4 pb;
        if (sc > -5.0e9f && (unsigned)ci < (unsigned)NANCH) pb = bx4[ci];
        else pb = make_float4(-4e9f, -4e9f, -4e9f, -4e9f);
        cbx4[i] = pb;
    }
}

// =====================================================================
// Kernel 4b: pairwise suppression bitmasks (proven).
// =====================================================================
__global__ __launch_bounds__(256) void nms_mask(
    const float* __restrict__ CBX, unsigned* __restrict__ MASK)
{
    const int rg = blockIdx.x, b = blockIdx.y, tid = threadIdx.x;
    const float4* cbx = (const float4*)CBX + (size_t)b * CAND_PAD;
    unsigned* mrow = MASK + (size_t)b * CAND_PAD * MWORDS;

    __shared__ float4 rb[64];
    __shared__ float  rar[64];
    __shared__ float4 cb[1024];
    __shared__ float  car[1024];

    if (tid < 64) {
        float4 v = cbx[rg * 64 + tid];
        rb[tid] = v;
        rar[tid] = (v.z - v.x + 1.f) * (v.w - v.y + 1.f);
    }
    __syncthreads();
    const int rl = tid >> 2;                  // row 0..63 within group
    const int wq = tid & 3;
    const float4 rv = rb[rl];
    const float  ra = rar[rl];
    const size_t rbase = (size_t)(rg * 64 + rl) * MWORDS;

    for (int jt = rg >> 4; jt < 6; jt++) {    // skip strictly-lower tiles
        __syncthreads();
        for (int e = tid; e < 1024; e += 256) {
            float4 v = cbx[jt * 1024 + e];
            cb[e] = v;
            car[e] = (v.z - v.x + 1.f) * (v.w - v.y + 1.f);
        }
        __syncthreads();
#pragma unroll
        for (int k = 0; k < 8; k++) {
            const int wt = wq + 4 * k;        // word in tile 0..31
            unsigned bits = 0;
            for (int bit = 0; bit < 32; bit++) {
                const int j = wt * 32 + bit;
                float4 cv = cb[j];
                float xx1 = fmaxf(rv.x, cv.x);
                float yy1 = fmaxf(rv.y, cv.y);
                float xx2 = fminf(rv.z, cv.z);
                float yy2 = fminf(rv.w, cv.w);
                float iw = fmaxf(xx2 - xx1 + 1.f, 0.f);
                float ih = fmaxf(yy2 - yy1 + 1.f, 0.f);
                float inter = iw * ih;
                float iou = inter / (ra + car[j] - inter);
                if (iou > 0.7f) bits |= (1u << bit);
            }
            mrow[rbase + jt * 32 + wt] = bits;
        }
    }
}

// =====================================================================
// Kernel 4c: scan v2 -- single wave (64 thr), 1-wave barriers (cheap),
// next-chunk diag prefetched before kept-row ORs (T14 issue-early).
// Logic identical to proven scan: keep i iff not suppressed by any
// kept j<i in sorted order; first 300 kept = exact greedy NMS.
// =====================================================================
__global__ __launch_bounds__(64) void nms_scan(
    const float* __restrict__ CSC, const float* __restrict__ CBX,
    const unsigned* __restrict__ MASK, float* __restrict__ out)
{
    const int b = blockIdx.x, lane = threadIdx.x;
    const float*  csc = CSC + (size_t)b * CAND_PAD;
    const float4* cbx = (const float4*)CBX + (size_t)b * CAND_PAD;
    const unsigned* mk = MASK + (size_t)b * CAND_PAD * MWORDS;

    __shared__ unsigned s_rm[MWORDS];

    float* rois = out + (size_t)b * 1500;
    float* oscr = out + 6000 + (size_t)b * 300;

    for (int i = lane; i < MWORDS; i += 64) s_rm[i] = 0u;
    for (int it = lane; it < POST_N; it += 64) {
        float* r = rois + it * 5;
        r[0] = (float)b; r[1] = 0.f; r[2] = 0.f; r[3] = 0.f; r[4] = 0.f;
        oscr[it] = 0.f;
    }
    __syncthreads();

    int cnt = 0;
    // prefetch chunk 0 diag words + score
    unsigned rlo = mk[(size_t)lane * MWORDS + 0];
    unsigned rhi = mk[(size_t)lane * MWORDS + 1];
    float    rsc = csc[lane];

    for (int c = 0; c < 94 && cnt < POST_N; c++) {
        unsigned gw = s_rm[2 * c + (lane >> 5)];
        bool alive = !((gw >> (lane & 31)) & 1u) && (rsc > -5.0e9f);
        u64 rem = __ballot(alive);
        u64 keptm = 0ull;
        while (rem) {
            int sl = __builtin_ctzll(rem);
            keptm |= 1ull << sl;
            unsigned blo = __shfl(rlo, sl);
            unsigned bhi = __shfl(rhi, sl);
            rem &= ~(((u64)bhi << 32) | (u64)blo);
            rem &= ~(1ull << sl);
        }
        // prefetch next chunk (overlaps with kept-row processing)
        if (c + 1 < 94) {
            const int i2 = (c + 1) * 64 + lane;
            rlo = mk[(size_t)i2 * MWORDS + 2 * (c + 1)];
            rhi = mk[(size_t)i2 * MWORDS + 2 * (c + 1) + 1];
            rsc = csc[i2];
        }
        // process kept rows of this chunk
        while (keptm && cnt < POST_N) {
            int sl = __builtin_ctzll(keptm);
            keptm &= keptm - 1ull;
            const int i = c * 64 + sl;
            const size_t rb = (size_t)i * MWORDS;
            s_rm[lane]       |= mk[rb + lane];
            s_rm[lane + 64]  |= mk[rb + lane + 64];
            s_rm[lane + 128] |= mk[rb + lane + 128];
            if (lane == 0) {
                float4 pb = cbx[i];
                float* r = rois + cnt * 5;
                r[1] = pb.x; r[2] = pb.y; r[3] = pb.z; r[4] = pb.w;
                oscr[cnt] = csc[i];
            }
            cnt++;
        }
        __syncthreads();   // 1-wave barrier: orders s_rm ORs before next read
    }
}

// =====================================================================
extern "C" void kernel_launch(void* const* d_in, const int* in_sizes, int n_in,
                              void* d_out, int out_size, void* d_ws, size_t ws_size,
                              hipStream_t stream)
{
    const float* base_feat = (const float*)d_in[0];
    const float* im_info   = (const float*)d_in[1];
    const float* conv_w    = (const float*)d_in[4];
    const float* conv_b    = (const float*)d_in[5];
    const float* cls_w     = (const float*)d_in[6];
    const float* cls_b     = (const float*)d_in[7];
    const float* bbox_w    = (const float*)d_in[8];
    const float* bbox_b    = (const float*)d_in[9];

    float* ws  = (float*)d_ws;
    float* X   = ws + X_OFF;
    float* SC  = ws + SC_OFF;
    float* BX  = ws + BX_OFF;
    float* CSC = ws + CSC_OFF;
    float* CBX = ws + CBX_OFF;
    int*   CIX = (int*)(ws + CIX_OFF);
    u16*   WTH = (u16*)(ws + WTH_OFF);
    u16*   WTL = (u16*)(ws + WTL_OFF);
    u16*   XHp = (u16*)(ws + XH_OFF);
    u16*   XLp = (u16*)(ws + XL_OFF);
    float* ZPf = ws + ZP_OFF;
    const u16* ZPu = (const u16*)ZPf;
    unsigned* MASK = (unsigned*)(ws + X_OFF);   // aliases X (dead after heads)
    float* out = (float*)d_out;

    hipLaunchKernelGGL(prep_wtk, dim3(18432), dim3(256), 0, stream,
                       conv_w, WTH, WTL, ZPf);
    hipLaunchKernelGGL(prep_act, dim3(4096), dim3(256), 0, stream,
                       base_feat, XHp, XLp);
    hipLaunchKernelGGL(conv3_mfma, dim3(128, 4), dim3(256), 0, stream,
                       WTH, WTL, XHp, XLp, ZPu, conv_b, X);
    hipLaunchKernelGGL(heads_kernel, dim3(64), dim3(256), 0, stream,
                       X, cls_w, cls_b, bbox_w, bbox_b, im_info, SC, BX);
    hipLaunchKernelGGL(select_kernel, dim3(4), dim3(1024), 0, stream,
                       SC, CSC, CIX);
    hipLaunchKernelGGL(sort_kernel, dim3(4), dim3(1024), 0, stream,
                       CSC, CBX, CIX, BX);
    hipLaunchKernelGGL(nms_mask, dim3(96, 4), dim3(256), 0, stream,
                       CBX, MASK);
    hipLaunchKernelGGL(nms_scan, dim3(4), dim3(64), 0, stream,
                       CSC, CBX, MASK, out);
}